// Round 3
// baseline (336.747 us; speedup 1.0000x reference)
//
#include <hip/hip_runtime.h>

// 8 x 512 x 512 f32 -> 17x17 windows @ stride 4 -> 124x124 windows/batch -> (8,68) means.
// Bitplane GLCM: per-(tile-row, level) bitmasks built by wave ballot; each lane holds its
// window's 17-bit row masks and computes co-occurrence counts with AND+POPCNT (v_bcnt has
// a built-in accumulator) in registers. No LDS histogram.
//
// R3: 6 waves/block (384 thr) for occupancy — R2's 2-wave blocks supplied only 4 waves/SIMD
// (measured 31% occupancy, VALUBusy 40%). Wave roles (offset pairs share one rolling row
// pass so each LDS row is loaded once per pair):
//   w0: stats + value histogram        w1: (0,1)k0 + (1,0)k2
//   w2: (0,2)k4 + (1,1)k1,k5           w3: (0,4)k8 + (1,-1)k3,k7
//   w4: (2,0)k6 + (3,3)k9              w5: (4,0)k10 + (3,-3)k11

#define G_MEAN_F 85.384f
#define G_STD_F  53.798f

__device__ constexpr int LO15[15] = {0,0,0,0,0,1,1,1,1,2,2,2,3,3,4};
__device__ constexpr int HI15[15] = {0,1,2,3,4,1,2,3,4,2,3,4,3,4,4};

__device__ __forceinline__ float wred(float v) {
#pragma unroll
  for (int m = 32; m; m >>= 1) v += __shfl_xor(v, m, 64);
  return v;
}

// Read one tile row's 4 level-masks (u64, 32B contiguous -> 2x ds_read_b128),
// slice this window's 17 bits per level; level 0 derived by complement.
__device__ __forceinline__ void load_row(const unsigned long long* mrow, int ly4, unsigned m[5]) {
  unsigned long long a = mrow[0], b = mrow[1], c = mrow[2], d = mrow[3];
  m[1] = (unsigned)(a >> ly4) & 0x1FFFFu;
  m[2] = (unsigned)(b >> ly4) & 0x1FFFFu;
  m[3] = (unsigned)(c >> ly4) & 0x1FFFFu;
  m[4] = (unsigned)(d >> ly4) & 0x1FFFFu;
  m[0] = 0x1FFFFu & ~(m[1] | m[2] | m[3] | m[4]);
}

// cnt[u] += popc(a_i & b_j) (+ popc(a_j & b_i) off-diag) for the 15 unordered bins.
__device__ __forceinline__ void upd(unsigned cnt[15], const unsigned a[5], const unsigned b[5]) {
#pragma unroll
  for (int u = 0; u < 15; ++u) {
    const int i = LO15[u], j = HI15[u];
    unsigned s = __popc(a[i] & b[j]);
    if (i != j) s += __popc(a[j] & b[i]);
    cnt[u] += s;
  }
}

// Apply column shift for offset DC then accumulate: a = upper row, b = lower row.
template<int DC>
__device__ __forceinline__ void updoff(unsigned cnt[15], const unsigned a[5], const unsigned b[5]) {
  unsigned as[5], bs[5];
#pragma unroll
  for (int v = 0; v < 5; ++v) {
    as[v] = (DC < 0) ? (a[v] >> (-DC)) : a[v];
    bs[v] = (DC > 0) ? (b[v] >> DC) : b[v];
  }
  upd(cnt, as, bs);
}

// GLCM feature epilogue (verified R1/R2): cnt[u] = symmetric-unordered pair counts.
__device__ __forceinline__ void emit(const unsigned cnt[15], float Np, bool valid,
                                     float* outb, int k0, int k1) {
  const float invN = 1.0f / Np;
  const float inv2N = 0.5f / Np;
  float con = 0.0f, hom = 0.0f, eac = 0.0f, ent = 0.0f;
  float P[5] = {0, 0, 0, 0, 0};
#pragma unroll
  for (int u = 0; u < 15; ++u) {
    const int lo = LO15[u], hi = HI15[u];
    const float m = (float)cnt[u];
    const float d2 = (float)((hi - lo) * (hi - lo));
    con += m * d2;
    hom += m * (1.0f / (1.0f + d2));
    if (lo == hi) {
      eac += m * m;
      P[lo] += 2.0f * m;
      float g = m * invN;
      ent -= g * __log2f(g + 1e-8f);
    } else {
      eac += 0.5f * m * m;
      P[lo] += m; P[hi] += m;
      float g = m * inv2N;
      ent -= 2.0f * g * __log2f(g + 1e-8f);
    }
  }
  con *= invN;
  hom *= invN;
  float ene = sqrtf(eac) * invN;
  float mu = 0.0f;
#pragma unroll
  for (int i = 0; i < 5; ++i) { P[i] *= inv2N; mu += (float)i * P[i]; }
  float s2 = 0.0f;
#pragma unroll
  for (int i = 0; i < 5; ++i) { float d = (float)i - mu; s2 = fmaf(P[i] * d, d, s2); }
  float sd = sqrtf(s2);
  float denom = sd * sd;
  float cov = 0.0f;
#pragma unroll
  for (int u = 0; u < 15; ++u)
    cov += ((float)cnt[u] * invN) * ((float)LO15[u] - mu) * ((float)HI15[u] - mu);
  float corr = (denom < 1e-15f) ? 1.0f : cov / fmaxf(denom, 1e-30f);

  if (!valid) { con = 0; hom = 0; ene = 0; corr = 0; ent = 0; }
  con = wred(con); hom = wred(hom); ene = wred(ene); corr = wred(corr); ent = wred(ent);
  if ((threadIdx.x & 63) == 0) {
    const float s = 1.0f / 15376.0f;
    unsafeAtomicAdd(outb + 8 + k0, con * s);
    unsafeAtomicAdd(outb + 20 + k0, hom * s);
    unsafeAtomicAdd(outb + 32 + k0, ene * s);
    unsafeAtomicAdd(outb + 44 + k0, corr * s);
    unsafeAtomicAdd(outb + 56 + k0, ent * s);
    if (k1 >= 0) {
      unsafeAtomicAdd(outb + 8 + k1, con * s);
      unsafeAtomicAdd(outb + 20 + k1, hom * s);
      unsafeAtomicAdd(outb + 32 + k1, ene * s);
      unsafeAtomicAdd(outb + 44 + k1, corr * s);
      unsafeAtomicAdd(outb + 56 + k1, ent * s);
    }
  }
}

// Two offsets (DRA,DCA)+(DRB,DCB) in ONE fully-unrolled rolling pass: each LDS row is
// loaded exactly once. Rotating buffer uses compile-time modulo indices (no reg moves).
template<int DRA, int DCA, int DRB, int DCB>
__device__ __forceinline__ void glcm_dual(const unsigned long long* mbase, int ly4,
                                          float NpA, float NpB, bool valid, float* outb,
                                          int kA0, int kA1, int kB0, int kB1) {
  constexpr int BUF = (DRB > DRA ? DRB : DRA) + 1;
  unsigned cntA[15], cntB[15];
#pragma unroll
  for (int u = 0; u < 15; ++u) { cntA[u] = 0; cntB[u] = 0; }
  unsigned buf[BUF][5];
#pragma unroll
  for (int r = 0; r < 17; ++r) {
    load_row(mbase + r * 5, ly4, buf[r % BUF]);
    if (r >= DRA) updoff<DCA>(cntA, buf[(r - DRA) % BUF], buf[r % BUF]);
    if (r >= DRB) updoff<DCB>(cntB, buf[(r - DRB) % BUF], buf[r % BUF]);
  }
  emit(cntA, NpA, valid, outb, kA0, kA1);
  emit(cntB, NpB, valid, outb, kB0, kB1);
}

__global__ __launch_bounds__(384)
void glcm_feat_kernel(const float* __restrict__ x, float* __restrict__ out) {
  __shared__ unsigned long long masks[45 * 5];  // [tile_row][level-1], slot 4 pad (1800 B)

  const int tid = threadIdx.x;
  const int lane = tid & 63;
  const int wid = tid >> 6;
  const int b = blockIdx.z;
  const int px0 = blockIdx.y * 32;
  const int py0 = blockIdx.x * 32;
  const float* xb = x + (size_t)b * 512 * 512;

  const float T1 = 0.5f;
  const float T2 = (float)(85.384 - 53.798);
  const float T3 = 85.384f;
  const float T4 = (float)(85.384 + 53.798);

  // Phase A: per-row level bitmasks via ballot (lane c = tile column c), 6 waves striped.
#pragma unroll 1
  for (int row = wid; row < 45; row += 6) {
    int gr = px0 + row; if (gr > 511) gr = 511;
    int gc = py0 + lane;
    float xv = 0.0f;
    if (lane < 45 && gc < 512) xv = xb[gr * 512 + gc];
    int q = (int)(xv >= T1) + (int)(xv >= T2) + (int)(xv >= T3) + (int)(xv >= T4);
    unsigned long long b1 = __ballot(q == 1);
    unsigned long long b2 = __ballot(q == 2);
    unsigned long long b3 = __ballot(q == 3);
    unsigned long long b4 = __ballot(q == 4);
    unsigned long long bv = b4;
    if (lane == 1) bv = b1; else if (lane == 2) bv = b2; else if (lane == 3) bv = b3;
    if (lane >= 1 && lane <= 4) masks[row * 5 + (lane - 1)] = bv;
  }
  __syncthreads();

  // Phase B: one window per lane (8x8 window tile); offsets split across 6 waves.
  const int lx = lane >> 3, ly = lane & 7;
  const int wx = blockIdx.y * 8 + lx;
  const int wy = blockIdx.x * 8 + ly;
  const bool valid = (wx < 124) && (wy < 124);
  const unsigned long long* mbase = masks + (lx * 4) * 5;
  const int ly4 = ly * 4;
  float* outb = out + b * 68;

  if (wid == 0) {
    // value histogram from level-count popcounts (one mask pass)
    unsigned nv1 = 0, nv2 = 0, nv3 = 0, nv4 = 0;
#pragma unroll
    for (int r = 0; r < 17; ++r) {
      unsigned m[5];
      load_row(mbase + r * 5, ly4, m);
      nv1 += __popc(m[1]); nv2 += __popc(m[2]);
      nv3 += __popc(m[3]); nv4 += __popc(m[4]);
    }
    unsigned tot = nv1 + nv2 + nv3 + nv4;
    float ti = (tot > 0) ? 1.0f / (float)tot : 0.0f;
    float h1 = (float)nv1 * ti, h2 = (float)nv2 * ti;
    float h3 = (float)nv3 * ti, h4 = (float)nv4 * ti;

    // float stats from global (tile is L1/L2 resident); clamps keep invalid lanes
    // in-bounds & 16B-aligned (their results are zeroed by `valid`).
    int r0 = px0 + lx * 4; if (r0 > 495) r0 = 495;
    int c0 = py0 + ly * 4; if (c0 > 492) c0 = 492;
    const float* fw = xb + (size_t)r0 * 512 + c0;
    float sum = 0.0f, ssq = 0.0f, mx = -1e30f, mn = 1e30f;
#pragma unroll 1
    for (int r = 0; r < 17; ++r) {
      const float* p = fw + r * 512;
      const float4* p4 = (const float4*)p;
#pragma unroll
      for (int w = 0; w < 4; ++w) {
        float4 f = p4[w];
        sum += f.x; ssq = fmaf(f.x, f.x, ssq); mx = fmaxf(mx, f.x); mn = fminf(mn, f.x);
        sum += f.y; ssq = fmaf(f.y, f.y, ssq); mx = fmaxf(mx, f.y); mn = fminf(mn, f.y);
        sum += f.z; ssq = fmaf(f.z, f.z, ssq); mx = fmaxf(mx, f.z); mn = fminf(mn, f.z);
        sum += f.w; ssq = fmaf(f.w, f.w, ssq); mx = fmaxf(mx, f.w); mn = fminf(mn, f.w);
      }
      float t = p[16];
      sum += t; ssq = fmaf(t, t, ssq); mx = fmaxf(mx, t); mn = fminf(mn, t);
    }
    float mean = sum * (1.0f / 289.0f);
    float var = fmaxf(ssq * (1.0f / 289.0f) - mean * mean, 0.0f);
    float fm = mean / G_MEAN_F;
    float fs = sqrtf(var) / G_STD_F;
    float fmx = (mx - fm) / G_STD_F;
    float fmn = (fm - mn) / G_STD_F;
    if (!valid) { fm = fs = fmx = fmn = h1 = h2 = h3 = h4 = 0.0f; }
    fm = wred(fm); fs = wred(fs); fmx = wred(fmx); fmn = wred(fmn);
    h1 = wred(h1); h2 = wred(h2); h3 = wred(h3); h4 = wred(h4);
    if (lane == 0) {
      const float s = 1.0f / 15376.0f;
      unsafeAtomicAdd(outb + 0, fm * s);
      unsafeAtomicAdd(outb + 1, fs * s);
      unsafeAtomicAdd(outb + 2, fmx * s);
      unsafeAtomicAdd(outb + 3, fmn * s);
      unsafeAtomicAdd(outb + 4, h1 * s);
      unsafeAtomicAdd(outb + 5, h2 * s);
      unsafeAtomicAdd(outb + 6, h3 * s);
      unsafeAtomicAdd(outb + 7, h4 * s);
    }
  } else if (wid == 1) {
    glcm_dual<0, 1, 1, 0>(mbase, ly4, 272.0f, 272.0f, valid, outb, 0, -1, 2, -1);
  } else if (wid == 2) {
    glcm_dual<0, 2, 1, 1>(mbase, ly4, 255.0f, 256.0f, valid, outb, 4, -1, 1, 5);
  } else if (wid == 3) {
    glcm_dual<0, 4, 1, -1>(mbase, ly4, 221.0f, 256.0f, valid, outb, 8, -1, 3, 7);
  } else if (wid == 4) {
    glcm_dual<2, 0, 3, 3>(mbase, ly4, 255.0f, 196.0f, valid, outb, 6, -1, 9, -1);
  } else {
    glcm_dual<4, 0, 3, -3>(mbase, ly4, 221.0f, 196.0f, valid, outb, 10, -1, 11, -1);
  }
}

extern "C" void kernel_launch(void* const* d_in, const int* in_sizes, int n_in,
                              void* d_out, int out_size, void* d_ws, size_t ws_size,
                              hipStream_t stream)
{
  const float* x = (const float*)d_in[0];
  float* out = (float*)d_out;
  hipMemsetAsync(out, 0, (size_t)out_size * sizeof(float), stream);
  dim3 grid(16, 16, 8);   // x: wy tiles, y: wx tiles, z: batch
  dim3 block(384);        // 6 waves: stats + 5 offset-pair workers
  glcm_feat_kernel<<<grid, block, 0, stream>>>(x, out);
}

// Round 4
// 281.468 us; speedup vs baseline: 1.1964x; 1.1964x over previous
//
#include <hip/hip_runtime.h>

// 8 x 512 x 512 f32 -> 17x17 windows @ stride 4 -> 124x124 windows/batch -> (8,68) means.
// Bitplane GLCM: per-(tile-row, level) bitmasks via wave ballot; co-occurrence counts by
// AND+POPCNT in registers. R4: 6 wave-roles split over THREE 2-wave blocks per tile
// (grid 48x16x8) for 12 waves/SIMD supply; all K-loops rolled to keep VGPR <= ~72
// (R3 post-mortem: full unroll -> 128 VGPR + 6-wave-block straggler tails -> 12% occ).
// Roles (role = blockIdx.x>>4):
//   r0: w0 stats+hist            w1 dual (0,1)k0 + (1,0)k2
//   r1: w0 dual (0,2)k4+(1,1)k1,k5   w1 dual (0,4)k8 + (1,-1)k3,k7
//   r2: w0 (2,0)k6 then (3,3)k9      w1 (4,0)k10 then (3,-3)k11

#define G_MEAN_F 85.384f
#define G_STD_F  53.798f

__device__ constexpr int LO15[15] = {0,0,0,0,0,1,1,1,1,2,2,2,3,3,4};
__device__ constexpr int HI15[15] = {0,1,2,3,4,1,2,3,4,2,3,4,3,4,4};

__device__ __forceinline__ float wred(float v) {
#pragma unroll
  for (int m = 32; m; m >>= 1) v += __shfl_xor(v, m, 64);
  return v;
}

// Read one tile row's 4 level-masks (u64, contiguous 32B), slice this window's 17 bits.
__device__ __forceinline__ void load_row(const unsigned long long* mrow, int ly4, unsigned m[5]) {
  unsigned long long a = mrow[0], b = mrow[1], c = mrow[2], d = mrow[3];
  m[1] = (unsigned)(a >> ly4) & 0x1FFFFu;
  m[2] = (unsigned)(b >> ly4) & 0x1FFFFu;
  m[3] = (unsigned)(c >> ly4) & 0x1FFFFu;
  m[4] = (unsigned)(d >> ly4) & 0x1FFFFu;
  m[0] = 0x1FFFFu & ~(m[1] | m[2] | m[3] | m[4]);
}

__device__ __forceinline__ void upd(unsigned cnt[15], const unsigned a[5], const unsigned b[5]) {
#pragma unroll
  for (int u = 0; u < 15; ++u) {
    const int i = LO15[u], j = HI15[u];
    unsigned s = __popc(a[i] & b[j]);
    if (i != j) s += __popc(a[j] & b[i]);
    cnt[u] += s;
  }
}

template<int DC>
__device__ __forceinline__ void updoff(unsigned cnt[15], const unsigned a[5], const unsigned b[5]) {
  unsigned as[5], bs[5];
#pragma unroll
  for (int v = 0; v < 5; ++v) {
    as[v] = (DC < 0) ? (a[v] >> (-DC)) : a[v];
    bs[v] = (DC > 0) ? (b[v] >> DC) : b[v];
  }
  upd(cnt, as, bs);
}

// GLCM feature epilogue (verified R1/R2): cnt[u] = symmetric-unordered pair counts.
__device__ __forceinline__ void emit(const unsigned cnt[15], float Np, bool valid,
                                     float* outb, int k0, int k1) {
  const float invN = 1.0f / Np;
  const float inv2N = 0.5f / Np;
  float con = 0.0f, hom = 0.0f, eac = 0.0f, ent = 0.0f;
  float P[5] = {0, 0, 0, 0, 0};
#pragma unroll
  for (int u = 0; u < 15; ++u) {
    const int lo = LO15[u], hi = HI15[u];
    const float m = (float)cnt[u];
    const float d2 = (float)((hi - lo) * (hi - lo));
    con += m * d2;
    hom += m * (1.0f / (1.0f + d2));
    if (lo == hi) {
      eac += m * m;
      P[lo] += 2.0f * m;
      float g = m * invN;
      ent -= g * __log2f(g + 1e-8f);
    } else {
      eac += 0.5f * m * m;
      P[lo] += m; P[hi] += m;
      float g = m * inv2N;
      ent -= 2.0f * g * __log2f(g + 1e-8f);
    }
  }
  con *= invN;
  hom *= invN;
  float ene = sqrtf(eac) * invN;
  float mu = 0.0f;
#pragma unroll
  for (int i = 0; i < 5; ++i) { P[i] *= inv2N; mu += (float)i * P[i]; }
  float s2 = 0.0f;
#pragma unroll
  for (int i = 0; i < 5; ++i) { float d = (float)i - mu; s2 = fmaf(P[i] * d, d, s2); }
  float sd = sqrtf(s2);
  float denom = sd * sd;
  float cov = 0.0f;
#pragma unroll
  for (int u = 0; u < 15; ++u)
    cov += ((float)cnt[u] * invN) * ((float)LO15[u] - mu) * ((float)HI15[u] - mu);
  float corr = (denom < 1e-15f) ? 1.0f : cov / fmaxf(denom, 1e-30f);

  if (!valid) { con = 0; hom = 0; ene = 0; corr = 0; ent = 0; }
  con = wred(con); hom = wred(hom); ene = wred(ene); corr = wred(corr); ent = wred(ent);
  if ((threadIdx.x & 63) == 0) {
    const float s = 1.0f / 15376.0f;
    unsafeAtomicAdd(outb + 8 + k0, con * s);
    unsafeAtomicAdd(outb + 20 + k0, hom * s);
    unsafeAtomicAdd(outb + 32 + k0, ene * s);
    unsafeAtomicAdd(outb + 44 + k0, corr * s);
    unsafeAtomicAdd(outb + 56 + k0, ent * s);
    if (k1 >= 0) {
      unsafeAtomicAdd(outb + 8 + k1, con * s);
      unsafeAtomicAdd(outb + 20 + k1, hom * s);
      unsafeAtomicAdd(outb + 32 + k1, ene * s);
      unsafeAtomicAdd(outb + 44 + k1, corr * s);
      unsafeAtomicAdd(outb + 56 + k1, ent * s);
    }
  }
}

// Two offsets, DRA in {0,1}, DRB in {0,1} (DRM=1): rolled loop, 2-row rolling buffer,
// each LDS row loaded once for both offsets.
template<int DRA, int DCA, int DRB, int DCB>
__device__ __forceinline__ void glcm_dual1(const unsigned long long* mbase, int ly4,
                                           float NpA, float NpB, bool valid, float* outb,
                                           int kA0, int kA1, int kB0, int kB1) {
  unsigned cntA[15], cntB[15];
#pragma unroll
  for (int u = 0; u < 15; ++u) { cntA[u] = 0; cntB[u] = 0; }
  unsigned p[5], c[5];
  load_row(mbase, ly4, p);
  if (DRA == 0) updoff<DCA>(cntA, p, p);
  if (DRB == 0) updoff<DCB>(cntB, p, p);
#pragma unroll 1
  for (int r = 1; r < 17; ++r) {
    load_row(mbase + r * 5, ly4, c);
    updoff<DCA>(cntA, DRA ? p : c, c);
    updoff<DCB>(cntB, DRB ? p : c, c);
#pragma unroll
    for (int v = 0; v < 5; ++v) p[v] = c[v];
  }
  emit(cntA, NpA, valid, outb, kA0, kA1);
  emit(cntB, NpB, valid, outb, kB0, kB1);
}

// Single offset, rolled rolling DR+1 row buffer (R2-style, VGPR-lean).
template<int DR, int DC>
__device__ __forceinline__ void glcm_one(const unsigned long long* mbase, int ly4,
                                         float Np, bool valid, float* outb, int k0, int k1) {
  unsigned cnt[15];
#pragma unroll
  for (int u = 0; u < 15; ++u) cnt[u] = 0;
  unsigned buf[DR + 1][5];
#pragma unroll
  for (int r = 0; r < DR; ++r) load_row(mbase + r * 5, ly4, buf[r]);
#pragma unroll 1
  for (int r = DR; r < 17; ++r) {
    load_row(mbase + r * 5, ly4, buf[DR]);
    updoff<DC>(cnt, buf[0], buf[DR]);
#pragma unroll
    for (int i = 0; i < DR; ++i)
#pragma unroll
      for (int v = 0; v < 5; ++v) buf[i][v] = buf[i + 1][v];
  }
  emit(cnt, Np, valid, outb, k0, k1);
}

__global__ __launch_bounds__(128)
void glcm_feat_kernel(const float* __restrict__ x, float* __restrict__ out) {
  __shared__ unsigned long long masks[45 * 5];  // [tile_row][level-1], slot 4 pad (1800 B)

  const int tid = threadIdx.x;
  const int lane = tid & 63;
  const int wid = tid >> 6;
  const int role = blockIdx.x >> 4;
  const int tyx = blockIdx.x & 15;
  const int b = blockIdx.z;
  const int px0 = blockIdx.y * 32;
  const int py0 = tyx * 32;
  const float* xb = x + (size_t)b * 512 * 512;

  const float T1 = 0.5f;
  const float T2 = (float)(85.384 - 53.798);
  const float T3 = 85.384f;
  const float T4 = (float)(85.384 + 53.798);

  // Phase A: per-row level bitmasks via ballot (lane c = tile column c), 2 waves striped.
#pragma unroll 1
  for (int row = wid; row < 45; row += 2) {
    int gr = px0 + row; if (gr > 511) gr = 511;
    int gc = py0 + lane;
    float xv = 0.0f;
    if (lane < 45 && gc < 512) xv = xb[gr * 512 + gc];
    int q = (int)(xv >= T1) + (int)(xv >= T2) + (int)(xv >= T3) + (int)(xv >= T4);
    unsigned long long b1 = __ballot(q == 1);
    unsigned long long b2 = __ballot(q == 2);
    unsigned long long b3 = __ballot(q == 3);
    unsigned long long b4 = __ballot(q == 4);
    unsigned long long bv = b4;
    if (lane == 1) bv = b1; else if (lane == 2) bv = b2; else if (lane == 3) bv = b3;
    if (lane >= 1 && lane <= 4) masks[row * 5 + (lane - 1)] = bv;
  }
  __syncthreads();

  // Phase B: one window per lane (8x8 window tile); roles across 3 blocks x 2 waves.
  const int lx = lane >> 3, ly = lane & 7;
  const int wx = blockIdx.y * 8 + lx;
  const int wy = tyx * 8 + ly;
  const bool valid = (wx < 124) && (wy < 124);
  const unsigned long long* mbase = masks + (lx * 4) * 5;
  const int ly4 = ly * 4;
  float* outb = out + b * 68;

  if (role == 0) {
    if (wid == 0) {
      // value histogram from level-count popcounts
      unsigned nv1 = 0, nv2 = 0, nv3 = 0, nv4 = 0;
#pragma unroll 1
      for (int r = 0; r < 17; ++r) {
        unsigned m[5];
        load_row(mbase + r * 5, ly4, m);
        nv1 += __popc(m[1]); nv2 += __popc(m[2]);
        nv3 += __popc(m[3]); nv4 += __popc(m[4]);
      }
      unsigned tot = nv1 + nv2 + nv3 + nv4;
      float ti = (tot > 0) ? 1.0f / (float)tot : 0.0f;
      float h1 = (float)nv1 * ti, h2 = (float)nv2 * ti;
      float h3 = (float)nv3 * ti, h4 = (float)nv4 * ti;

      // float stats from global (L1/L2-resident tile); clamps keep invalid lanes
      // in-bounds & 16B-aligned (results zeroed by `valid`).
      int r0 = px0 + lx * 4; if (r0 > 495) r0 = 495;
      int c0 = py0 + ly * 4; if (c0 > 492) c0 = 492;
      const float* fw = xb + (size_t)r0 * 512 + c0;
      float sum = 0.0f, ssq = 0.0f, mx = -1e30f, mn = 1e30f;
#pragma unroll 1
      for (int r = 0; r < 17; ++r) {
        const float* p = fw + r * 512;
        const float4* p4 = (const float4*)p;
#pragma unroll
        for (int w = 0; w < 4; ++w) {
          float4 f = p4[w];
          sum += f.x; ssq = fmaf(f.x, f.x, ssq); mx = fmaxf(mx, f.x); mn = fminf(mn, f.x);
          sum += f.y; ssq = fmaf(f.y, f.y, ssq); mx = fmaxf(mx, f.y); mn = fminf(mn, f.y);
          sum += f.z; ssq = fmaf(f.z, f.z, ssq); mx = fmaxf(mx, f.z); mn = fminf(mn, f.z);
          sum += f.w; ssq = fmaf(f.w, f.w, ssq); mx = fmaxf(mx, f.w); mn = fminf(mn, f.w);
        }
        float t = p[16];
        sum += t; ssq = fmaf(t, t, ssq); mx = fmaxf(mx, t); mn = fminf(mn, t);
      }
      float mean = sum * (1.0f / 289.0f);
      float var = fmaxf(ssq * (1.0f / 289.0f) - mean * mean, 0.0f);
      float fm = mean / G_MEAN_F;
      float fs = sqrtf(var) / G_STD_F;
      float fmx = (mx - fm) / G_STD_F;
      float fmn = (fm - mn) / G_STD_F;
      if (!valid) { fm = fs = fmx = fmn = h1 = h2 = h3 = h4 = 0.0f; }
      fm = wred(fm); fs = wred(fs); fmx = wred(fmx); fmn = wred(fmn);
      h1 = wred(h1); h2 = wred(h2); h3 = wred(h3); h4 = wred(h4);
      if (lane == 0) {
        const float s = 1.0f / 15376.0f;
        unsafeAtomicAdd(outb + 0, fm * s);
        unsafeAtomicAdd(outb + 1, fs * s);
        unsafeAtomicAdd(outb + 2, fmx * s);
        unsafeAtomicAdd(outb + 3, fmn * s);
        unsafeAtomicAdd(outb + 4, h1 * s);
        unsafeAtomicAdd(outb + 5, h2 * s);
        unsafeAtomicAdd(outb + 6, h3 * s);
        unsafeAtomicAdd(outb + 7, h4 * s);
      }
    } else {
      glcm_dual1<0, 1, 1, 0>(mbase, ly4, 272.0f, 272.0f, valid, outb, 0, -1, 2, -1);
    }
  } else if (role == 1) {
    if (wid == 0) {
      glcm_dual1<0, 2, 1, 1>(mbase, ly4, 255.0f, 256.0f, valid, outb, 4, -1, 1, 5);
    } else {
      glcm_dual1<0, 4, 1, -1>(mbase, ly4, 221.0f, 256.0f, valid, outb, 8, -1, 3, 7);
    }
  } else {
    if (wid == 0) {
      glcm_one<2, 0>(mbase, ly4, 255.0f, valid, outb, 6, -1);
      glcm_one<3, 3>(mbase, ly4, 196.0f, valid, outb, 9, -1);
    } else {
      glcm_one<4, 0>(mbase, ly4, 221.0f, valid, outb, 10, -1);
      glcm_one<3, -3>(mbase, ly4, 196.0f, valid, outb, 11, -1);
    }
  }
}

extern "C" void kernel_launch(void* const* d_in, const int* in_sizes, int n_in,
                              void* d_out, int out_size, void* d_ws, size_t ws_size,
                              hipStream_t stream)
{
  const float* x = (const float*)d_in[0];
  float* out = (float*)d_out;
  hipMemsetAsync(out, 0, (size_t)out_size * sizeof(float), stream);
  dim3 grid(48, 16, 8);   // x: role(3) x wy-tile(16), y: wx-tile(16), z: batch
  dim3 block(128);        // 2 waves per block
  glcm_feat_kernel<<<grid, block, 0, stream>>>(x, out);
}

// Round 5
// 232.111 us; speedup vs baseline: 1.4508x; 1.2126x over previous
//
#include <hip/hip_runtime.h>

// 8 x 512 x 512 f32 -> 17x17 windows @ stride 4 -> 124x124 windows/batch -> (8,68) means.
// R5: two kernels. Kernel 1 builds per-(batch,row,level) 512-bit masks ONCE via ballot
// (d_ws, 1.18 MB). Kernel 2 = R4 phase B (verified) with phase A replaced by cheap
// L2-hot mask loads (R4 post-mortem: 3x-duplicated ballot phase A = 4.5K stall-cyc/block).
// Roles (role = blockIdx.x>>4), 3 blocks x 2 waves per 8x8-window tile:
//   r0: w0 stats+hist                w1 dual (0,1)k0 + (1,0)k2
//   r1: w0 dual (0,2)k4+(1,1)k1,k5   w1 dual (0,4)k8 + (1,-1)k3,k7
//   r2: w0 (2,0)k6 then (3,3)k9      w1 (4,0)k10 then (3,-3)k11
// ws layout: u64 mg[b][512][9 segs][4 levs]; seg 8 = zero pad (tile cols past 511).

#define G_MEAN_F 85.384f
#define G_STD_F  53.798f

__device__ constexpr int LO15[15] = {0,0,0,0,0,1,1,1,1,2,2,2,3,3,4};
__device__ constexpr int HI15[15] = {0,1,2,3,4,1,2,3,4,2,3,4,3,4,4};

__device__ __forceinline__ float wred(float v) {
#pragma unroll
  for (int m = 32; m; m >>= 1) v += __shfl_xor(v, m, 64);
  return v;
}

__device__ __forceinline__ void load_row(const unsigned long long* mrow, int ly4, unsigned m[5]) {
  unsigned long long a = mrow[0], b = mrow[1], c = mrow[2], d = mrow[3];
  m[1] = (unsigned)(a >> ly4) & 0x1FFFFu;
  m[2] = (unsigned)(b >> ly4) & 0x1FFFFu;
  m[3] = (unsigned)(c >> ly4) & 0x1FFFFu;
  m[4] = (unsigned)(d >> ly4) & 0x1FFFFu;
  m[0] = 0x1FFFFu & ~(m[1] | m[2] | m[3] | m[4]);
}

__device__ __forceinline__ void upd(unsigned cnt[15], const unsigned a[5], const unsigned b[5]) {
#pragma unroll
  for (int u = 0; u < 15; ++u) {
    const int i = LO15[u], j = HI15[u];
    unsigned s = __popc(a[i] & b[j]);
    if (i != j) s += __popc(a[j] & b[i]);
    cnt[u] += s;
  }
}

template<int DC>
__device__ __forceinline__ void updoff(unsigned cnt[15], const unsigned a[5], const unsigned b[5]) {
  unsigned as[5], bs[5];
#pragma unroll
  for (int v = 0; v < 5; ++v) {
    as[v] = (DC < 0) ? (a[v] >> (-DC)) : a[v];
    bs[v] = (DC > 0) ? (b[v] >> DC) : b[v];
  }
  upd(cnt, as, bs);
}

// GLCM feature epilogue (verified R1-R4): cnt[u] = symmetric-unordered pair counts.
__device__ __forceinline__ void emit(const unsigned cnt[15], float Np, bool valid,
                                     float* outb, int k0, int k1) {
  const float invN = 1.0f / Np;
  const float inv2N = 0.5f / Np;
  float con = 0.0f, hom = 0.0f, eac = 0.0f, ent = 0.0f;
  float P[5] = {0, 0, 0, 0, 0};
#pragma unroll
  for (int u = 0; u < 15; ++u) {
    const int lo = LO15[u], hi = HI15[u];
    const float m = (float)cnt[u];
    const float d2 = (float)((hi - lo) * (hi - lo));
    con += m * d2;
    hom += m * (1.0f / (1.0f + d2));
    if (lo == hi) {
      eac += m * m;
      P[lo] += 2.0f * m;
      float g = m * invN;
      ent -= g * __log2f(g + 1e-8f);
    } else {
      eac += 0.5f * m * m;
      P[lo] += m; P[hi] += m;
      float g = m * inv2N;
      ent -= 2.0f * g * __log2f(g + 1e-8f);
    }
  }
  con *= invN;
  hom *= invN;
  float ene = sqrtf(eac) * invN;
  float mu = 0.0f;
#pragma unroll
  for (int i = 0; i < 5; ++i) { P[i] *= inv2N; mu += (float)i * P[i]; }
  float s2 = 0.0f;
#pragma unroll
  for (int i = 0; i < 5; ++i) { float d = (float)i - mu; s2 = fmaf(P[i] * d, d, s2); }
  float sd = sqrtf(s2);
  float denom = sd * sd;
  float cov = 0.0f;
#pragma unroll
  for (int u = 0; u < 15; ++u)
    cov += ((float)cnt[u] * invN) * ((float)LO15[u] - mu) * ((float)HI15[u] - mu);
  float corr = (denom < 1e-15f) ? 1.0f : cov / fmaxf(denom, 1e-30f);

  if (!valid) { con = 0; hom = 0; ene = 0; corr = 0; ent = 0; }
  con = wred(con); hom = wred(hom); ene = wred(ene); corr = wred(corr); ent = wred(ent);
  if ((threadIdx.x & 63) == 0) {
    const float s = 1.0f / 15376.0f;
    unsafeAtomicAdd(outb + 8 + k0, con * s);
    unsafeAtomicAdd(outb + 20 + k0, hom * s);
    unsafeAtomicAdd(outb + 32 + k0, ene * s);
    unsafeAtomicAdd(outb + 44 + k0, corr * s);
    unsafeAtomicAdd(outb + 56 + k0, ent * s);
    if (k1 >= 0) {
      unsafeAtomicAdd(outb + 8 + k1, con * s);
      unsafeAtomicAdd(outb + 20 + k1, hom * s);
      unsafeAtomicAdd(outb + 32 + k1, ene * s);
      unsafeAtomicAdd(outb + 44 + k1, corr * s);
      unsafeAtomicAdd(outb + 56 + k1, ent * s);
    }
  }
}

// Two offsets with row-deltas in {0,1}: rolled loop, each LDS row loaded once for both.
template<int DRA, int DCA, int DRB, int DCB>
__device__ __forceinline__ void glcm_dual1(const unsigned long long* mbase, int ly4,
                                           float NpA, float NpB, bool valid, float* outb,
                                           int kA0, int kA1, int kB0, int kB1) {
  unsigned cntA[15], cntB[15];
#pragma unroll
  for (int u = 0; u < 15; ++u) { cntA[u] = 0; cntB[u] = 0; }
  unsigned p[5], c[5];
  load_row(mbase, ly4, p);
  if (DRA == 0) updoff<DCA>(cntA, p, p);
  if (DRB == 0) updoff<DCB>(cntB, p, p);
#pragma unroll 1
  for (int r = 1; r < 17; ++r) {
    load_row(mbase + r * 5, ly4, c);
    updoff<DCA>(cntA, DRA ? p : c, c);
    updoff<DCB>(cntB, DRB ? p : c, c);
#pragma unroll
    for (int v = 0; v < 5; ++v) p[v] = c[v];
  }
  emit(cntA, NpA, valid, outb, kA0, kA1);
  emit(cntB, NpB, valid, outb, kB0, kB1);
}

// Single offset, rolled rolling DR+1 row buffer (VGPR-lean).
template<int DR, int DC>
__device__ __forceinline__ void glcm_one(const unsigned long long* mbase, int ly4,
                                         float Np, bool valid, float* outb, int k0, int k1) {
  unsigned cnt[15];
#pragma unroll
  for (int u = 0; u < 15; ++u) cnt[u] = 0;
  unsigned buf[DR + 1][5];
#pragma unroll
  for (int r = 0; r < DR; ++r) load_row(mbase + r * 5, ly4, buf[r]);
#pragma unroll 1
  for (int r = DR; r < 17; ++r) {
    load_row(mbase + r * 5, ly4, buf[DR]);
    updoff<DC>(cnt, buf[0], buf[DR]);
#pragma unroll
    for (int i = 0; i < DR; ++i)
#pragma unroll
      for (int v = 0; v < 5; ++v) buf[i][v] = buf[i + 1][v];
  }
  emit(cnt, Np, valid, outb, k0, k1);
}

// ---------- Kernel 1: whole-image mask precompute ----------
// One wave per (batch,row); 8 coalesced 64-px segments -> 4 ballots each.
__global__ __launch_bounds__(64)
void mask_build_kernel(const float* __restrict__ x, unsigned long long* __restrict__ mg) {
  const int lane = threadIdx.x;
  const int r = blockIdx.x;
  const int b = blockIdx.y;
  const float* xr = x + ((size_t)b * 512 + r) * 512;
  unsigned long long* mr = mg + ((size_t)b * 512 + r) * 36;  // 9 segs x 4 levs

  const float T1 = 0.5f;
  const float T2 = (float)(85.384 - 53.798);
  const float T3 = 85.384f;
  const float T4 = (float)(85.384 + 53.798);

#pragma unroll 1
  for (int seg = 0; seg < 8; ++seg) {
    float xv = xr[seg * 64 + lane];
    int q = (int)(xv >= T1) + (int)(xv >= T2) + (int)(xv >= T3) + (int)(xv >= T4);
    unsigned long long b1 = __ballot(q == 1);
    unsigned long long b2 = __ballot(q == 2);
    unsigned long long b3 = __ballot(q == 3);
    unsigned long long b4 = __ballot(q == 4);
    if (lane < 4) {
      unsigned long long bv = (lane == 0) ? b1 : (lane == 1) ? b2 : (lane == 2) ? b3 : b4;
      mr[seg * 4 + lane] = bv;
    }
  }
  if (lane < 4) mr[32 + lane] = 0;  // seg 8 pad (cols >= 512 read as level 0)
}

// ---------- Kernel 2: features ----------
__global__ __launch_bounds__(128)
void glcm_feat_kernel(const float* __restrict__ x,
                      const unsigned long long* __restrict__ mg,
                      float* __restrict__ out) {
  __shared__ unsigned long long masks[45 * 5];  // [tile_row][lev], slot 4 pad (1800 B)

  const int tid = threadIdx.x;
  const int lane = tid & 63;
  const int wid = tid >> 6;
  const int role = blockIdx.x >> 4;
  const int tyx = blockIdx.x & 15;
  const int b = blockIdx.z;
  const int px0 = blockIdx.y * 32;
  const int py0 = tyx * 32;
  const float* xb = x + (size_t)b * 512 * 512;

  // Phase A: slice 45-bit tile rows out of the precomputed masks (L2-hot, 2 rounds).
  const int s0 = py0 >> 6;
  const int sh = py0 & 63;  // 0 or 32
  const unsigned long long* mgb = mg + (size_t)b * 512 * 36;
#pragma unroll 1
  for (int t = tid; t < 180; t += 128) {
    int row = t >> 2, lev = t & 3;
    int gr = px0 + row; if (gr > 511) gr = 511;   // matches R2-R4 row clamp
    const unsigned long long* p = mgb + (size_t)gr * 36 + s0 * 4 + lev;
    unsigned long long w0 = p[0];
    unsigned long long w1 = p[4];                  // next seg (incl. zero pad seg 8)
    masks[row * 5 + lev] = sh ? ((w0 >> 32) | (w1 << 32)) : w0;
  }
  __syncthreads();

  // Phase B (verified R4): one window per lane; roles across 3 blocks x 2 waves.
  const int lx = lane >> 3, ly = lane & 7;
  const int wx = blockIdx.y * 8 + lx;
  const int wy = tyx * 8 + ly;
  const bool valid = (wx < 124) && (wy < 124);
  const unsigned long long* mbase = masks + (lx * 4) * 5;
  const int ly4 = ly * 4;
  float* outb = out + b * 68;

  if (role == 0) {
    if (wid == 0) {
      unsigned nv1 = 0, nv2 = 0, nv3 = 0, nv4 = 0;
#pragma unroll 1
      for (int r = 0; r < 17; ++r) {
        unsigned m[5];
        load_row(mbase + r * 5, ly4, m);
        nv1 += __popc(m[1]); nv2 += __popc(m[2]);
        nv3 += __popc(m[3]); nv4 += __popc(m[4]);
      }
      unsigned tot = nv1 + nv2 + nv3 + nv4;
      float ti = (tot > 0) ? 1.0f / (float)tot : 0.0f;
      float h1 = (float)nv1 * ti, h2 = (float)nv2 * ti;
      float h3 = (float)nv3 * ti, h4 = (float)nv4 * ti;

      int r0 = px0 + lx * 4; if (r0 > 495) r0 = 495;
      int c0 = py0 + ly * 4; if (c0 > 492) c0 = 492;
      const float* fw = xb + (size_t)r0 * 512 + c0;
      float sum = 0.0f, ssq = 0.0f, mx = -1e30f, mn = 1e30f;
#pragma unroll 1
      for (int r = 0; r < 17; ++r) {
        const float* p = fw + r * 512;
        const float4* p4 = (const float4*)p;
#pragma unroll
        for (int w = 0; w < 4; ++w) {
          float4 f = p4[w];
          sum += f.x; ssq = fmaf(f.x, f.x, ssq); mx = fmaxf(mx, f.x); mn = fminf(mn, f.x);
          sum += f.y; ssq = fmaf(f.y, f.y, ssq); mx = fmaxf(mx, f.y); mn = fminf(mn, f.y);
          sum += f.z; ssq = fmaf(f.z, f.z, ssq); mx = fmaxf(mx, f.z); mn = fminf(mn, f.z);
          sum += f.w; ssq = fmaf(f.w, f.w, ssq); mx = fmaxf(mx, f.w); mn = fminf(mn, f.w);
        }
        float t = p[16];
        sum += t; ssq = fmaf(t, t, ssq); mx = fmaxf(mx, t); mn = fminf(mn, t);
      }
      float mean = sum * (1.0f / 289.0f);
      float var = fmaxf(ssq * (1.0f / 289.0f) - mean * mean, 0.0f);
      float fm = mean / G_MEAN_F;
      float fs = sqrtf(var) / G_STD_F;
      float fmx = (mx - fm) / G_STD_F;
      float fmn = (fm - mn) / G_STD_F;
      if (!valid) { fm = fs = fmx = fmn = h1 = h2 = h3 = h4 = 0.0f; }
      fm = wred(fm); fs = wred(fs); fmx = wred(fmx); fmn = wred(fmn);
      h1 = wred(h1); h2 = wred(h2); h3 = wred(h3); h4 = wred(h4);
      if (lane == 0) {
        const float s = 1.0f / 15376.0f;
        unsafeAtomicAdd(outb + 0, fm * s);
        unsafeAtomicAdd(outb + 1, fs * s);
        unsafeAtomicAdd(outb + 2, fmx * s);
        unsafeAtomicAdd(outb + 3, fmn * s);
        unsafeAtomicAdd(outb + 4, h1 * s);
        unsafeAtomicAdd(outb + 5, h2 * s);
        unsafeAtomicAdd(outb + 6, h3 * s);
        unsafeAtomicAdd(outb + 7, h4 * s);
      }
    } else {
      glcm_dual1<0, 1, 1, 0>(mbase, ly4, 272.0f, 272.0f, valid, outb, 0, -1, 2, -1);
    }
  } else if (role == 1) {
    if (wid == 0) {
      glcm_dual1<0, 2, 1, 1>(mbase, ly4, 255.0f, 256.0f, valid, outb, 4, -1, 1, 5);
    } else {
      glcm_dual1<0, 4, 1, -1>(mbase, ly4, 221.0f, 256.0f, valid, outb, 8, -1, 3, 7);
    }
  } else {
    if (wid == 0) {
      glcm_one<2, 0>(mbase, ly4, 255.0f, valid, outb, 6, -1);
      glcm_one<3, 3>(mbase, ly4, 196.0f, valid, outb, 9, -1);
    } else {
      glcm_one<4, 0>(mbase, ly4, 221.0f, valid, outb, 10, -1);
      glcm_one<3, -3>(mbase, ly4, 196.0f, valid, outb, 11, -1);
    }
  }
}

extern "C" void kernel_launch(void* const* d_in, const int* in_sizes, int n_in,
                              void* d_out, int out_size, void* d_ws, size_t ws_size,
                              hipStream_t stream)
{
  const float* x = (const float*)d_in[0];
  float* out = (float*)d_out;
  unsigned long long* mg = (unsigned long long*)d_ws;  // needs 8*512*36*8 = 1.18 MB

  hipMemsetAsync(out, 0, (size_t)out_size * sizeof(float), stream);
  mask_build_kernel<<<dim3(512, 8), dim3(64), 0, stream>>>(x, mg);
  glcm_feat_kernel<<<dim3(48, 16, 8), dim3(128), 0, stream>>>(x, mg, out);
}

// Round 6
// 119.812 us; speedup vs baseline: 2.8106x; 1.9373x over previous
//
#include <hip/hip_runtime.h>

// 8 x 512 x 512 f32 -> 17x17 windows @ stride 4 -> 124x124 windows/batch -> (8,68) means.
// R6: three kernels. (1) whole-image level-bitmask precompute (verified R5). (2) feature
// kernel = R5 verified phase A/B, but output partials go to UNIQUE d_ws slots via plain
// stores — R1-R5 post-mortem: ~139K device-scope fp32 atomics onto 40 cache lines
// (cross-XCD line ping-pong ~100+cyc each ~ 350K cyc) was the duration floor in EVERY
// round. (3) tiny reduction kernel sums 256 tile-partials per (batch,channel).
// Roles (role = blockIdx.x>>4), 3 blocks x 2 waves per 8x8-window tile:
//   r0: w0 stats+hist                w1 dual (0,1)k0 + (1,0)k2
//   r1: w0 dual (0,2)k4+(1,1)k1,k5   w1 dual (0,4)k8 + (1,-1)k3,k7
//   r2: w0 (2,0)k6 then (3,3)k9      w1 (4,0)k10 then (3,-3)k11
// ws: u64 mg[8][512][9][4] (1.18 MB) then float part[8][68][256] (557 KB).

#define G_MEAN_F 85.384f
#define G_STD_F  53.798f
#define MASK_WS_BYTES (8u * 512u * 36u * 8u)

__device__ constexpr int LO15[15] = {0,0,0,0,0,1,1,1,1,2,2,2,3,3,4};
__device__ constexpr int HI15[15] = {0,1,2,3,4,1,2,3,4,2,3,4,3,4,4};

__device__ __forceinline__ float wred(float v) {
#pragma unroll
  for (int m = 32; m; m >>= 1) v += __shfl_xor(v, m, 64);
  return v;
}

__device__ __forceinline__ void load_row(const unsigned long long* mrow, int ly4, unsigned m[5]) {
  unsigned long long a = mrow[0], b = mrow[1], c = mrow[2], d = mrow[3];
  m[1] = (unsigned)(a >> ly4) & 0x1FFFFu;
  m[2] = (unsigned)(b >> ly4) & 0x1FFFFu;
  m[3] = (unsigned)(c >> ly4) & 0x1FFFFu;
  m[4] = (unsigned)(d >> ly4) & 0x1FFFFu;
  m[0] = 0x1FFFFu & ~(m[1] | m[2] | m[3] | m[4]);
}

__device__ __forceinline__ void upd(unsigned cnt[15], const unsigned a[5], const unsigned b[5]) {
#pragma unroll
  for (int u = 0; u < 15; ++u) {
    const int i = LO15[u], j = HI15[u];
    unsigned s = __popc(a[i] & b[j]);
    if (i != j) s += __popc(a[j] & b[i]);
    cnt[u] += s;
  }
}

template<int DC>
__device__ __forceinline__ void updoff(unsigned cnt[15], const unsigned a[5], const unsigned b[5]) {
  unsigned as[5], bs[5];
#pragma unroll
  for (int v = 0; v < 5; ++v) {
    as[v] = (DC < 0) ? (a[v] >> (-DC)) : a[v];
    bs[v] = (DC > 0) ? (b[v] >> DC) : b[v];
  }
  upd(cnt, as, bs);
}

// GLCM feature epilogue (math verified R1-R5). pt0 = per-(batch,tile) partial base;
// channel ch's slot is pt0[ch*256]. Plain stores — no contention, wave retires fast.
__device__ __forceinline__ void emit(const unsigned cnt[15], float Np, bool valid,
                                     float* pt0, int k0, int k1) {
  const float invN = 1.0f / Np;
  const float inv2N = 0.5f / Np;
  float con = 0.0f, hom = 0.0f, eac = 0.0f, ent = 0.0f;
  float P[5] = {0, 0, 0, 0, 0};
#pragma unroll
  for (int u = 0; u < 15; ++u) {
    const int lo = LO15[u], hi = HI15[u];
    const float m = (float)cnt[u];
    const float d2 = (float)((hi - lo) * (hi - lo));
    con += m * d2;
    hom += m * (1.0f / (1.0f + d2));
    if (lo == hi) {
      eac += m * m;
      P[lo] += 2.0f * m;
      float g = m * invN;
      ent -= g * __log2f(g + 1e-8f);
    } else {
      eac += 0.5f * m * m;
      P[lo] += m; P[hi] += m;
      float g = m * inv2N;
      ent -= 2.0f * g * __log2f(g + 1e-8f);
    }
  }
  con *= invN;
  hom *= invN;
  float ene = sqrtf(eac) * invN;
  float mu = 0.0f;
#pragma unroll
  for (int i = 0; i < 5; ++i) { P[i] *= inv2N; mu += (float)i * P[i]; }
  float s2 = 0.0f;
#pragma unroll
  for (int i = 0; i < 5; ++i) { float d = (float)i - mu; s2 = fmaf(P[i] * d, d, s2); }
  float sd = sqrtf(s2);
  float denom = sd * sd;
  float cov = 0.0f;
#pragma unroll
  for (int u = 0; u < 15; ++u)
    cov += ((float)cnt[u] * invN) * ((float)LO15[u] - mu) * ((float)HI15[u] - mu);
  float corr = (denom < 1e-15f) ? 1.0f : cov / fmaxf(denom, 1e-30f);

  if (!valid) { con = 0; hom = 0; ene = 0; corr = 0; ent = 0; }
  con = wred(con); hom = wred(hom); ene = wred(ene); corr = wred(corr); ent = wred(ent);
  if ((threadIdx.x & 63) == 0) {
    const float s = 1.0f / 15376.0f;
    pt0[(8 + k0) * 256] = con * s;
    pt0[(20 + k0) * 256] = hom * s;
    pt0[(32 + k0) * 256] = ene * s;
    pt0[(44 + k0) * 256] = corr * s;
    pt0[(56 + k0) * 256] = ent * s;
    if (k1 >= 0) {
      pt0[(8 + k1) * 256] = con * s;
      pt0[(20 + k1) * 256] = hom * s;
      pt0[(32 + k1) * 256] = ene * s;
      pt0[(44 + k1) * 256] = corr * s;
      pt0[(56 + k1) * 256] = ent * s;
    }
  }
}

// Two offsets with row-deltas in {0,1}: rolled loop, each LDS row loaded once for both.
template<int DRA, int DCA, int DRB, int DCB>
__device__ __forceinline__ void glcm_dual1(const unsigned long long* mbase, int ly4,
                                           float NpA, float NpB, bool valid, float* pt0,
                                           int kA0, int kA1, int kB0, int kB1) {
  unsigned cntA[15], cntB[15];
#pragma unroll
  for (int u = 0; u < 15; ++u) { cntA[u] = 0; cntB[u] = 0; }
  unsigned p[5], c[5];
  load_row(mbase, ly4, p);
  if (DRA == 0) updoff<DCA>(cntA, p, p);
  if (DRB == 0) updoff<DCB>(cntB, p, p);
#pragma unroll 1
  for (int r = 1; r < 17; ++r) {
    load_row(mbase + r * 5, ly4, c);
    updoff<DCA>(cntA, DRA ? p : c, c);
    updoff<DCB>(cntB, DRB ? p : c, c);
#pragma unroll
    for (int v = 0; v < 5; ++v) p[v] = c[v];
  }
  emit(cntA, NpA, valid, pt0, kA0, kA1);
  emit(cntB, NpB, valid, pt0, kB0, kB1);
}

// Single offset, rolled rolling DR+1 row buffer (VGPR-lean).
template<int DR, int DC>
__device__ __forceinline__ void glcm_one(const unsigned long long* mbase, int ly4,
                                         float Np, bool valid, float* pt0, int k0, int k1) {
  unsigned cnt[15];
#pragma unroll
  for (int u = 0; u < 15; ++u) cnt[u] = 0;
  unsigned buf[DR + 1][5];
#pragma unroll
  for (int r = 0; r < DR; ++r) load_row(mbase + r * 5, ly4, buf[r]);
#pragma unroll 1
  for (int r = DR; r < 17; ++r) {
    load_row(mbase + r * 5, ly4, buf[DR]);
    updoff<DC>(cnt, buf[0], buf[DR]);
#pragma unroll
    for (int i = 0; i < DR; ++i)
#pragma unroll
      for (int v = 0; v < 5; ++v) buf[i][v] = buf[i + 1][v];
  }
  emit(cnt, Np, valid, pt0, k0, k1);
}

// ---------- Kernel 1: whole-image mask precompute (verified R5) ----------
__global__ __launch_bounds__(64)
void mask_build_kernel(const float* __restrict__ x, unsigned long long* __restrict__ mg) {
  const int lane = threadIdx.x;
  const int r = blockIdx.x;
  const int b = blockIdx.y;
  const float* xr = x + ((size_t)b * 512 + r) * 512;
  unsigned long long* mr = mg + ((size_t)b * 512 + r) * 36;  // 9 segs x 4 levs

  const float T1 = 0.5f;
  const float T2 = (float)(85.384 - 53.798);
  const float T3 = 85.384f;
  const float T4 = (float)(85.384 + 53.798);

#pragma unroll 1
  for (int seg = 0; seg < 8; ++seg) {
    float xv = xr[seg * 64 + lane];
    int q = (int)(xv >= T1) + (int)(xv >= T2) + (int)(xv >= T3) + (int)(xv >= T4);
    unsigned long long b1 = __ballot(q == 1);
    unsigned long long b2 = __ballot(q == 2);
    unsigned long long b3 = __ballot(q == 3);
    unsigned long long b4 = __ballot(q == 4);
    if (lane < 4) {
      unsigned long long bv = (lane == 0) ? b1 : (lane == 1) ? b2 : (lane == 2) ? b3 : b4;
      mr[seg * 4 + lane] = bv;
    }
  }
  if (lane < 4) mr[32 + lane] = 0;  // seg 8 pad
}

// ---------- Kernel 2: features -> per-tile partials in d_ws ----------
__global__ __launch_bounds__(128)
void glcm_feat_kernel(const float* __restrict__ x,
                      const unsigned long long* __restrict__ mg,
                      float* __restrict__ part) {
  __shared__ unsigned long long masks[45 * 5];  // [tile_row][lev], slot 4 pad (1800 B)

  const int tid = threadIdx.x;
  const int lane = tid & 63;
  const int wid = tid >> 6;
  const int role = blockIdx.x >> 4;
  const int tyx = blockIdx.x & 15;
  const int b = blockIdx.z;
  const int px0 = blockIdx.y * 32;
  const int py0 = tyx * 32;
  const float* xb = x + (size_t)b * 512 * 512;

  // Phase A: slice 45-bit tile rows out of precomputed masks (L2-hot, 2 rounds).
  const int s0 = py0 >> 6;
  const int sh = py0 & 63;  // 0 or 32
  const unsigned long long* mgb = mg + (size_t)b * 512 * 36;
#pragma unroll 1
  for (int t = tid; t < 180; t += 128) {
    int row = t >> 2, lev = t & 3;
    int gr = px0 + row; if (gr > 511) gr = 511;
    const unsigned long long* p = mgb + (size_t)gr * 36 + s0 * 4 + lev;
    unsigned long long w0 = p[0];
    unsigned long long w1 = p[4];
    masks[row * 5 + lev] = sh ? ((w0 >> 32) | (w1 << 32)) : w0;
  }
  __syncthreads();

  // Phase B (verified R4/R5): one window per lane; roles across 3 blocks x 2 waves.
  const int lx = lane >> 3, ly = lane & 7;
  const int wx = blockIdx.y * 8 + lx;
  const int wy = tyx * 8 + ly;
  const bool valid = (wx < 124) && (wy < 124);
  const unsigned long long* mbase = masks + (lx * 4) * 5;
  const int ly4 = ly * 4;
  const int tile = blockIdx.y * 16 + tyx;                 // 0..255
  float* pt0 = part + (size_t)b * 68 * 256 + tile;        // channel ch at pt0[ch*256]

  if (role == 0) {
    if (wid == 0) {
      unsigned nv1 = 0, nv2 = 0, nv3 = 0, nv4 = 0;
#pragma unroll 1
      for (int r = 0; r < 17; ++r) {
        unsigned m[5];
        load_row(mbase + r * 5, ly4, m);
        nv1 += __popc(m[1]); nv2 += __popc(m[2]);
        nv3 += __popc(m[3]); nv4 += __popc(m[4]);
      }
      unsigned tot = nv1 + nv2 + nv3 + nv4;
      float ti = (tot > 0) ? 1.0f / (float)tot : 0.0f;
      float h1 = (float)nv1 * ti, h2 = (float)nv2 * ti;
      float h3 = (float)nv3 * ti, h4 = (float)nv4 * ti;

      int r0 = px0 + lx * 4; if (r0 > 495) r0 = 495;
      int c0 = py0 + ly * 4; if (c0 > 492) c0 = 492;
      const float* fw = xb + (size_t)r0 * 512 + c0;
      float sum = 0.0f, ssq = 0.0f, mx = -1e30f, mn = 1e30f;
#pragma unroll 1
      for (int r = 0; r < 17; ++r) {
        const float* p = fw + r * 512;
        const float4* p4 = (const float4*)p;
#pragma unroll
        for (int w = 0; w < 4; ++w) {
          float4 f = p4[w];
          sum += f.x; ssq = fmaf(f.x, f.x, ssq); mx = fmaxf(mx, f.x); mn = fminf(mn, f.x);
          sum += f.y; ssq = fmaf(f.y, f.y, ssq); mx = fmaxf(mx, f.y); mn = fminf(mn, f.y);
          sum += f.z; ssq = fmaf(f.z, f.z, ssq); mx = fmaxf(mx, f.z); mn = fminf(mn, f.z);
          sum += f.w; ssq = fmaf(f.w, f.w, ssq); mx = fmaxf(mx, f.w); mn = fminf(mn, f.w);
        }
        float t = p[16];
        sum += t; ssq = fmaf(t, t, ssq); mx = fmaxf(mx, t); mn = fminf(mn, t);
      }
      float mean = sum * (1.0f / 289.0f);
      float var = fmaxf(ssq * (1.0f / 289.0f) - mean * mean, 0.0f);
      float fm = mean / G_MEAN_F;
      float fs = sqrtf(var) / G_STD_F;
      float fmx = (mx - fm) / G_STD_F;
      float fmn = (fm - mn) / G_STD_F;
      if (!valid) { fm = fs = fmx = fmn = h1 = h2 = h3 = h4 = 0.0f; }
      fm = wred(fm); fs = wred(fs); fmx = wred(fmx); fmn = wred(fmn);
      h1 = wred(h1); h2 = wred(h2); h3 = wred(h3); h4 = wred(h4);
      if (lane == 0) {
        const float s = 1.0f / 15376.0f;
        pt0[0 * 256] = fm * s;
        pt0[1 * 256] = fs * s;
        pt0[2 * 256] = fmx * s;
        pt0[3 * 256] = fmn * s;
        pt0[4 * 256] = h1 * s;
        pt0[5 * 256] = h2 * s;
        pt0[6 * 256] = h3 * s;
        pt0[7 * 256] = h4 * s;
      }
    } else {
      glcm_dual1<0, 1, 1, 0>(mbase, ly4, 272.0f, 272.0f, valid, pt0, 0, -1, 2, -1);
    }
  } else if (role == 1) {
    if (wid == 0) {
      glcm_dual1<0, 2, 1, 1>(mbase, ly4, 255.0f, 256.0f, valid, pt0, 4, -1, 1, 5);
    } else {
      glcm_dual1<0, 4, 1, -1>(mbase, ly4, 221.0f, 256.0f, valid, pt0, 8, -1, 3, 7);
    }
  } else {
    if (wid == 0) {
      glcm_one<2, 0>(mbase, ly4, 255.0f, valid, pt0, 6, -1);
      glcm_one<3, 3>(mbase, ly4, 196.0f, valid, pt0, 9, -1);
    } else {
      glcm_one<4, 0>(mbase, ly4, 221.0f, valid, pt0, 10, -1);
      glcm_one<3, -3>(mbase, ly4, 196.0f, valid, pt0, 11, -1);
    }
  }
}

// ---------- Kernel 3: reduce 256 tile-partials per (batch,channel) ----------
__global__ __launch_bounds__(64)
void reduce_kernel(const float* __restrict__ part, float* __restrict__ out) {
  const int ch = blockIdx.x;     // 0..67
  const int b = blockIdx.y;      // 0..7
  const int lane = threadIdx.x;  // 0..63
  const float4* p = (const float4*)(part + ((size_t)b * 68 + ch) * 256);
  float4 f = p[lane];
  float v = (f.x + f.y) + (f.z + f.w);
  v = wred(v);
  if (lane == 0) out[b * 68 + ch] = v;
}

extern "C" void kernel_launch(void* const* d_in, const int* in_sizes, int n_in,
                              void* d_out, int out_size, void* d_ws, size_t ws_size,
                              hipStream_t stream)
{
  const float* x = (const float*)d_in[0];
  float* out = (float*)d_out;
  unsigned long long* mg = (unsigned long long*)d_ws;             // 1.18 MB
  float* part = (float*)((char*)d_ws + MASK_WS_BYTES);            // 557 KB

  mask_build_kernel<<<dim3(512, 8), dim3(64), 0, stream>>>(x, mg);
  glcm_feat_kernel<<<dim3(48, 16, 8), dim3(128), 0, stream>>>(x, mg, part);
  reduce_kernel<<<dim3(68, 8), dim3(64), 0, stream>>>(part, out);
}

// Round 7
// 114.261 us; speedup vs baseline: 2.9472x; 1.0486x over previous
//
#include <hip/hip_runtime.h>

// 8 x 512 x 512 f32 -> 17x17 windows @ stride 4 -> 124x124 windows/batch -> (8,68) means.
// R7: R6 pipeline (mask precompute -> feature -> reduce; unique-slot partials, no global
// atomics) + two VALU cuts in the feature kernel:
//  (a) 2 vertically-adjacent windows per lane (identical column slice -> identical row-pair
//      contributions). Phase counters E1 (rows [0,4)), S ([4,17-DR)), E2 ([17-DR,21-DR));
//      cnt_w1 = E1+S, cnt_w2 = S+E2. Shared rows computed once.
//  (b) off-diagonal bins: a_i&b_j and a_j&b_i are disjoint -> popc of the OR (v_and_or_b32).
// Tile = 16x8 windows per wave; grid: role(3) x ty(16) | tx(8) | batch(8).
// Roles (2 waves each): r0: stats+hist | (0,1)k0,(1,0)k2 ; r1: (0,2)k4,(1,1)k1&5 |
//   (0,4)k8,(1,-1)k3&7 ; r2: (2,0)k6,(3,3)k9 | (4,0)k10,(3,-3)k11.
// ws: u64 mg[8][512][9][4] (1.18 MB) then float part[8][68][128] (278 KB).

#define G_MEAN_F 85.384f
#define G_STD_F  53.798f
#define MASK_WS_BYTES (8u * 512u * 36u * 8u)

__device__ constexpr int LO15[15] = {0,0,0,0,0,1,1,1,1,2,2,2,3,3,4};
__device__ constexpr int HI15[15] = {0,1,2,3,4,1,2,3,4,2,3,4,3,4,4};

__device__ __forceinline__ float wred(float v) {
#pragma unroll
  for (int m = 32; m; m >>= 1) v += __shfl_xor(v, m, 64);
  return v;
}

__device__ __forceinline__ void load_row(const unsigned long long* mrow, int ly4, unsigned m[5]) {
  unsigned long long a = mrow[0], b = mrow[1], c = mrow[2], d = mrow[3];
  m[1] = (unsigned)(a >> ly4) & 0x1FFFFu;
  m[2] = (unsigned)(b >> ly4) & 0x1FFFFu;
  m[3] = (unsigned)(c >> ly4) & 0x1FFFFu;
  m[4] = (unsigned)(d >> ly4) & 0x1FFFFu;
  m[0] = 0x1FFFFu & ~(m[1] | m[2] | m[3] | m[4]);
}

// (b): off-diag sets are disjoint -> single popc of the union (and + and_or + bcnt).
__device__ __forceinline__ void upd(unsigned cnt[15], const unsigned a[5], const unsigned b[5]) {
#pragma unroll
  for (int u = 0; u < 15; ++u) {
    const int i = LO15[u], j = HI15[u];
    unsigned t = a[i] & b[j];
    if (i != j) t |= a[j] & b[i];
    cnt[u] += __popc(t);
  }
}

// One row-pair (a-row = mk[row], b-row = mk[row+DR]) accumulated into cnt.
template<int DR, int DC>
__device__ __forceinline__ void row_pair(unsigned cnt[15], const unsigned long long* mk,
                                         int row, int ly4) {
  unsigned a[5], b[5];
  load_row(mk + row * 5, ly4, a);
  if (DR > 0) load_row(mk + (row + DR) * 5, ly4, b);
  unsigned as[5], bs[5];
#pragma unroll
  for (int v = 0; v < 5; ++v) {
    unsigned bb = (DR > 0) ? b[v] : a[v];
    as[v] = (DC < 0) ? (a[v] >> (-DC)) : a[v];
    bs[v] = (DC > 0) ? (bb >> DC) : bb;
  }
  upd(cnt, as, bs);
}

// Per-window GLCM features from symmetric-unordered pair counts (math verified R1-R6).
__device__ __forceinline__ void feat5(const unsigned cnt[15], float Np,
                                      float& con, float& hom, float& ene,
                                      float& corr, float& ent) {
  const float invN = 1.0f / Np;
  const float inv2N = 0.5f / Np;
  con = 0.0f; hom = 0.0f; ent = 0.0f;
  float eac = 0.0f;
  float P[5] = {0, 0, 0, 0, 0};
#pragma unroll
  for (int u = 0; u < 15; ++u) {
    const int lo = LO15[u], hi = HI15[u];
    const float m = (float)cnt[u];
    const float d2 = (float)((hi - lo) * (hi - lo));
    con += m * d2;
    hom += m * (1.0f / (1.0f + d2));
    if (lo == hi) {
      eac += m * m;
      P[lo] += 2.0f * m;
      float g = m * invN;
      ent -= g * __log2f(g + 1e-8f);
    } else {
      eac += 0.5f * m * m;
      P[lo] += m; P[hi] += m;
      float g = m * inv2N;
      ent -= 2.0f * g * __log2f(g + 1e-8f);
    }
  }
  con *= invN;
  hom *= invN;
  ene = sqrtf(eac) * invN;
  float mu = 0.0f;
#pragma unroll
  for (int i = 0; i < 5; ++i) { P[i] *= inv2N; mu += (float)i * P[i]; }
  float s2 = 0.0f;
#pragma unroll
  for (int i = 0; i < 5; ++i) { float d = (float)i - mu; s2 = fmaf(P[i] * d, d, s2); }
  float denom = s2;   // std_i*std_j with std_i==std_j
  float cov = 0.0f;
#pragma unroll
  for (int u = 0; u < 15; ++u)
    cov += ((float)cnt[u] * invN) * ((float)LO15[u] - mu) * ((float)HI15[u] - mu);
  corr = (denom < 1e-15f) ? 1.0f : cov / fmaxf(denom, 1e-30f);
}

// Emit both packed windows' features (summed, validity-masked) to unique partial slots.
__device__ __forceinline__ void emit2(const unsigned c1[15], const unsigned c2[15], float Np,
                                      bool v1, bool v2, float* pt0, int k0, int k1) {
  float con1, hom1, ene1, cor1, ent1, con2, hom2, ene2, cor2, ent2;
  feat5(c1, Np, con1, hom1, ene1, cor1, ent1);
  feat5(c2, Np, con2, hom2, ene2, cor2, ent2);
  if (!v1) { con1 = 0; hom1 = 0; ene1 = 0; cor1 = 0; ent1 = 0; }
  if (!v2) { con2 = 0; hom2 = 0; ene2 = 0; cor2 = 0; ent2 = 0; }
  float con = wred(con1 + con2), hom = wred(hom1 + hom2), ene = wred(ene1 + ene2);
  float cor = wred(cor1 + cor2), ent = wred(ent1 + ent2);
  if ((threadIdx.x & 63) == 0) {
    const float s = 1.0f / 15376.0f;
    pt0[(8 + k0) * 128] = con * s;
    pt0[(20 + k0) * 128] = hom * s;
    pt0[(32 + k0) * 128] = ene * s;
    pt0[(44 + k0) * 128] = cor * s;
    pt0[(56 + k0) * 128] = ent * s;
    if (k1 >= 0) {
      pt0[(8 + k1) * 128] = con * s;
      pt0[(20 + k1) * 128] = hom * s;
      pt0[(32 + k1) * 128] = ene * s;
      pt0[(44 + k1) * 128] = cor * s;
      pt0[(56 + k1) * 128] = ent * s;
    }
  }
}

// (a): one offset over the lane's 2 vertically-adjacent windows via E1/S/E2 phases.
template<int DR, int DC>
__device__ __forceinline__ void glcm_pass(const unsigned long long* mk, int s, int ly4,
                                          float Np, bool v1, bool v2, float* pt0,
                                          int k0, int k1) {
  unsigned A[15], S[15], B[15];
#pragma unroll
  for (int u = 0; u < 15; ++u) { A[u] = 0; S[u] = 0; B[u] = 0; }
#pragma unroll 1
  for (int R = 0; R < 4; ++R) row_pair<DR, DC>(A, mk, s + R, ly4);
#pragma unroll 1
  for (int R = 4; R < 17 - DR; ++R) row_pair<DR, DC>(S, mk, s + R, ly4);
#pragma unroll 1
  for (int R = 17 - DR; R < 21 - DR; ++R) row_pair<DR, DC>(B, mk, s + R, ly4);
#pragma unroll
  for (int u = 0; u < 15; ++u) { A[u] += S[u]; B[u] += S[u]; }
  emit2(A, B, Np, v1, v2, pt0, k0, k1);
}

// ---------- Kernel 1: whole-image mask precompute (verified R5/R6) ----------
__global__ __launch_bounds__(64)
void mask_build_kernel(const float* __restrict__ x, unsigned long long* __restrict__ mg) {
  const int lane = threadIdx.x;
  const int r = blockIdx.x;
  const int b = blockIdx.y;
  const float* xr = x + ((size_t)b * 512 + r) * 512;
  unsigned long long* mr = mg + ((size_t)b * 512 + r) * 36;

  const float T1 = 0.5f;
  const float T2 = (float)(85.384 - 53.798);
  const float T3 = 85.384f;
  const float T4 = (float)(85.384 + 53.798);

#pragma unroll 1
  for (int seg = 0; seg < 8; ++seg) {
    float xv = xr[seg * 64 + lane];
    int q = (int)(xv >= T1) + (int)(xv >= T2) + (int)(xv >= T3) + (int)(xv >= T4);
    unsigned long long b1 = __ballot(q == 1);
    unsigned long long b2 = __ballot(q == 2);
    unsigned long long b3 = __ballot(q == 3);
    unsigned long long b4 = __ballot(q == 4);
    if (lane < 4) {
      unsigned long long bv = (lane == 0) ? b1 : (lane == 1) ? b2 : (lane == 2) ? b3 : b4;
      mr[seg * 4 + lane] = bv;
    }
  }
  if (lane < 4) mr[32 + lane] = 0;  // seg 8 pad
}

// ---------- Kernel 2: features -> per-tile partials ----------
__global__ __launch_bounds__(128)
void glcm_feat_kernel(const float* __restrict__ x,
                      const unsigned long long* __restrict__ mg,
                      float* __restrict__ part) {
  __shared__ unsigned long long masks[77 * 5];  // [tile_row][lev], slot 4 pad (3080 B)

  const int tid = threadIdx.x;
  const int lane = tid & 63;
  const int wid = tid >> 6;
  const int role = blockIdx.x >> 4;
  const int ty = blockIdx.x & 15;
  const int tx = blockIdx.y;
  const int b = blockIdx.z;
  const int px0 = tx * 64;
  const int py0 = ty * 32;
  const float* xb = x + (size_t)b * 512 * 512;

  // Phase A: slice 45-bit tile rows from precomputed masks (L2-hot).
  const int s0 = py0 >> 6;
  const int sh = py0 & 63;  // 0 or 32
  const unsigned long long* mgb = mg + (size_t)b * 512 * 36;
#pragma unroll 1
  for (int t = tid; t < 77 * 4; t += 128) {
    int row = t >> 2, lev = t & 3;
    int gr = px0 + row; if (gr > 511) gr = 511;
    const unsigned long long* p = mgb + (size_t)gr * 36 + s0 * 4 + lev;
    unsigned long long w0 = p[0];
    unsigned long long w1 = p[4];
    masks[row * 5 + lev] = sh ? ((w0 >> 32) | (w1 << 32)) : w0;
  }
  __syncthreads();

  // Lane = (lxp, ly): window pair wx1 = tx*16 + 2*lxp, wx2 = wx1+1; wy = ty*8 + ly.
  const int lxp = lane >> 3, ly = lane & 7;
  const int wx1 = tx * 16 + 2 * lxp;
  const int wy = ty * 8 + ly;
  const bool vy = (wy < 124);
  const bool v1 = (wx1 < 124) && vy;
  const bool v2 = (wx1 + 1 < 124) && vy;
  const int s = 8 * lxp;        // tile-local pixel row of w1
  const int ly4 = ly * 4;
  const int tile = tx * 16 + ty;                          // 0..127
  float* pt0 = part + (size_t)b * 68 * 128 + tile;        // channel ch at pt0[ch*128]

  if (role == 0) {
    if (wid == 0) {
      // ---- hist phases from mask popcounts ----
      unsigned hA[4] = {0,0,0,0}, hS[4] = {0,0,0,0}, hB[4] = {0,0,0,0};
#pragma unroll 1
      for (int R = 0; R < 21; ++R) {
        unsigned m[5];
        load_row(masks + (s + R) * 5, ly4, m);
        unsigned* h = (R < 4) ? hA : (R < 17) ? hS : hB;
#pragma unroll
        for (int v = 0; v < 4; ++v) h[v] += __popc(m[v + 1]);
      }
      // ---- stats phases from global float rows ----
      int sp = px0 + s; if (sp > 488) sp = 488;        // max valid even-window base
      int c0 = py0 + ly4; if (c0 > 492) c0 = 492;
      const float* fw = xb + (size_t)sp * 512 + c0;
      float sA = 0, qA = 0, sS = 0, qS = 0, sB = 0, qB = 0;
      float mxA = -1e30f, mnA = 1e30f, mxS = -1e30f, mnS = 1e30f, mxB = -1e30f, mnB = 1e30f;
#pragma unroll 1
      for (int r = 0; r < 21; ++r) {
        const float* p = fw + r * 512;
        const float4* p4 = (const float4*)p;
        float rs = 0, rq = 0, rmx = -1e30f, rmn = 1e30f;
#pragma unroll
        for (int w = 0; w < 4; ++w) {
          float4 f = p4[w];
          rs += f.x; rq = fmaf(f.x, f.x, rq); rmx = fmaxf(rmx, f.x); rmn = fminf(rmn, f.x);
          rs += f.y; rq = fmaf(f.y, f.y, rq); rmx = fmaxf(rmx, f.y); rmn = fminf(rmn, f.y);
          rs += f.z; rq = fmaf(f.z, f.z, rq); rmx = fmaxf(rmx, f.z); rmn = fminf(rmn, f.z);
          rs += f.w; rq = fmaf(f.w, f.w, rq); rmx = fmaxf(rmx, f.w); rmn = fminf(rmn, f.w);
        }
        float t = p[16];
        rs += t; rq = fmaf(t, t, rq); rmx = fmaxf(rmx, t); rmn = fminf(rmn, t);
        if (r < 4)       { sA += rs; qA += rq; mxA = fmaxf(mxA, rmx); mnA = fminf(mnA, rmn); }
        else if (r < 17) { sS += rs; qS += rq; mxS = fmaxf(mxS, rmx); mnS = fminf(mnS, rmn); }
        else             { sB += rs; qB += rq; mxB = fmaxf(mxB, rmx); mnB = fminf(mnB, rmn); }
      }
      float ch[8][2];
#pragma unroll
      for (int w = 0; w < 2; ++w) {
        float sum = w ? (sS + sB) : (sA + sS);
        float ssq = w ? (qS + qB) : (qA + qS);
        float mx = w ? fmaxf(mxS, mxB) : fmaxf(mxA, mxS);
        float mn = w ? fminf(mnS, mnB) : fminf(mnA, mnS);
        unsigned t1 = w ? (hS[0] + hB[0]) : (hA[0] + hS[0]);
        unsigned t2 = w ? (hS[1] + hB[1]) : (hA[1] + hS[1]);
        unsigned t3 = w ? (hS[2] + hB[2]) : (hA[2] + hS[2]);
        unsigned t4 = w ? (hS[3] + hB[3]) : (hA[3] + hS[3]);
        float mean = sum * (1.0f / 289.0f);
        float var = fmaxf(ssq * (1.0f / 289.0f) - mean * mean, 0.0f);
        float fm = mean / G_MEAN_F;
        ch[0][w] = fm;
        ch[1][w] = sqrtf(var) / G_STD_F;
        ch[2][w] = (mx - fm) / G_STD_F;
        ch[3][w] = (fm - mn) / G_STD_F;
        unsigned tot = t1 + t2 + t3 + t4;
        float ti = (tot > 0) ? 1.0f / (float)tot : 0.0f;
        ch[4][w] = (float)t1 * ti;
        ch[5][w] = (float)t2 * ti;
        ch[6][w] = (float)t3 * ti;
        ch[7][w] = (float)t4 * ti;
      }
#pragma unroll
      for (int c = 0; c < 8; ++c) {
        float f = (v1 ? ch[c][0] : 0.0f) + (v2 ? ch[c][1] : 0.0f);
        f = wred(f);
        if (lane == 0) pt0[c * 128] = f * (1.0f / 15376.0f);
      }
    } else {
      glcm_pass<0, 1>(masks, s, ly4, 272.0f, v1, v2, pt0, 0, -1);
      glcm_pass<1, 0>(masks, s, ly4, 272.0f, v1, v2, pt0, 2, -1);
    }
  } else if (role == 1) {
    if (wid == 0) {
      glcm_pass<0, 2>(masks, s, ly4, 255.0f, v1, v2, pt0, 4, -1);
      glcm_pass<1, 1>(masks, s, ly4, 256.0f, v1, v2, pt0, 1, 5);
    } else {
      glcm_pass<0, 4>(masks, s, ly4, 221.0f, v1, v2, pt0, 8, -1);
      glcm_pass<1, -1>(masks, s, ly4, 256.0f, v1, v2, pt0, 3, 7);
    }
  } else {
    if (wid == 0) {
      glcm_pass<2, 0>(masks, s, ly4, 255.0f, v1, v2, pt0, 6, -1);
      glcm_pass<3, 3>(masks, s, ly4, 196.0f, v1, v2, pt0, 9, -1);
    } else {
      glcm_pass<4, 0>(masks, s, ly4, 221.0f, v1, v2, pt0, 10, -1);
      glcm_pass<3, -3>(masks, s, ly4, 196.0f, v1, v2, pt0, 11, -1);
    }
  }
}

// ---------- Kernel 3: reduce 128 tile-partials per (batch,channel) ----------
__global__ __launch_bounds__(64)
void reduce_kernel(const float* __restrict__ part, float* __restrict__ out) {
  const int ch = blockIdx.x;
  const int b = blockIdx.y;
  const int lane = threadIdx.x;
  const float2* p = (const float2*)(part + ((size_t)b * 68 + ch) * 128);
  float2 f = p[lane];
  float v = f.x + f.y;
  v = wred(v);
  if (lane == 0) out[b * 68 + ch] = v;
}

extern "C" void kernel_launch(void* const* d_in, const int* in_sizes, int n_in,
                              void* d_out, int out_size, void* d_ws, size_t ws_size,
                              hipStream_t stream)
{
  const float* x = (const float*)d_in[0];
  float* out = (float*)d_out;
  unsigned long long* mg = (unsigned long long*)d_ws;         // 1.18 MB
  float* part = (float*)((char*)d_ws + MASK_WS_BYTES);        // 278 KB

  mask_build_kernel<<<dim3(512, 8), dim3(64), 0, stream>>>(x, mg);
  glcm_feat_kernel<<<dim3(48, 8, 8), dim3(128), 0, stream>>>(x, mg, part);
  reduce_kernel<<<dim3(68, 8), dim3(64), 0, stream>>>(part, out);
}

// Round 8
// 113.435 us; speedup vs baseline: 2.9686x; 1.0073x over previous
//
#include <hip/hip_runtime.h>

// 8 x 512 x 512 f32 -> 17x17 windows @ stride 4 -> 124x124 windows/batch -> (8,68) means.
// R8: R7 pipeline (mask precompute -> feature -> reduce; unique-slot partials) with the
// feature kernel re-sliced for occupancy: 12 wave-units per tile spread over SIX 2-wave
// blocks (12,288 waves = 12/SIMD supply; R7 supplied 6/SIMD -> 26.7% occ, VALUBusy 59%).
// Each GLCM pass handles 2 vertically-adjacent windows per lane (phase counters
// E1/S/E2: w1=E1+S, w2=S+E2) and loads each mask row ONCE (rolling shift-buffer,
// compile-time indices — R7 regression: it loaded 2 rows/pair for DR>0).
// Off-diag bins: a_i&b_j | a_j&b_i disjoint -> one popc (v_and + v_and_or + v_bcnt).
// Units (u = blockIdx.x>>4, 2 waves each):
//   u0: stats-float | hist (both light -> paired so no heavy wave idles beside them)
//   u1: (0,1)k0 | (1,0)k2     u2: (0,2)k4 | (1,1)k1,k5   u3: (0,4)k8 | (1,-1)k3,k7
//   u4: (2,0)k6 | (3,3)k9     u5: (4,0)k10 | (3,-3)k11
// ws: u64 mg[8][512][9][4] (1.18 MB) then float part[8][68][128] (278 KB).

#define G_MEAN_F 85.384f
#define G_STD_F  53.798f
#define MASK_WS_BYTES (8u * 512u * 36u * 8u)

__device__ constexpr int LO15[15] = {0,0,0,0,0,1,1,1,1,2,2,2,3,3,4};
__device__ constexpr int HI15[15] = {0,1,2,3,4,1,2,3,4,2,3,4,3,4,4};

__device__ __forceinline__ float wred(float v) {
#pragma unroll
  for (int m = 32; m; m >>= 1) v += __shfl_xor(v, m, 64);
  return v;
}

// Read one tile row's 4 level-masks (u64, contiguous 32B), slice this window's 17 bits.
__device__ __forceinline__ void load_row(const unsigned long long* mrow, int ly4, unsigned m[5]) {
  unsigned long long a = mrow[0], b = mrow[1], c = mrow[2], d = mrow[3];
  m[1] = (unsigned)(a >> ly4) & 0x1FFFFu;
  m[2] = (unsigned)(b >> ly4) & 0x1FFFFu;
  m[3] = (unsigned)(c >> ly4) & 0x1FFFFu;
  m[4] = (unsigned)(d >> ly4) & 0x1FFFFu;
  m[0] = 0x1FFFFu & ~(m[1] | m[2] | m[3] | m[4]);
}

// cnt[u] += popc over 15 unordered bins; off-diag sets disjoint -> popc of the union.
// Column shift DC applied here (a = upper row, b = lower row).
template<int DC>
__device__ __forceinline__ void updoff(unsigned cnt[15], const unsigned a[5], const unsigned b[5]) {
  unsigned as[5], bs[5];
#pragma unroll
  for (int v = 0; v < 5; ++v) {
    as[v] = (DC < 0) ? (a[v] >> (-DC)) : a[v];
    bs[v] = (DC > 0) ? (b[v] >> DC) : b[v];
  }
#pragma unroll
  for (int u = 0; u < 15; ++u) {
    const int i = LO15[u], j = HI15[u];
    unsigned t = as[i] & bs[j];
    if (i != j) t |= as[j] & bs[i];
    cnt[u] += __popc(t);
  }
}

// Per-window GLCM features from symmetric-unordered pair counts (math verified R1-R7).
__device__ __forceinline__ void feat5(const unsigned cnt[15], float Np,
                                      float& con, float& hom, float& ene,
                                      float& corr, float& ent) {
  const float invN = 1.0f / Np;
  const float inv2N = 0.5f / Np;
  con = 0.0f; hom = 0.0f; ent = 0.0f;
  float eac = 0.0f;
  float P[5] = {0, 0, 0, 0, 0};
#pragma unroll
  for (int u = 0; u < 15; ++u) {
    const int lo = LO15[u], hi = HI15[u];
    const float m = (float)cnt[u];
    const float d2 = (float)((hi - lo) * (hi - lo));
    con += m * d2;
    hom += m * (1.0f / (1.0f + d2));
    if (lo == hi) {
      eac += m * m;
      P[lo] += 2.0f * m;
      float g = m * invN;
      ent -= g * __log2f(g + 1e-8f);
    } else {
      eac += 0.5f * m * m;
      P[lo] += m; P[hi] += m;
      float g = m * inv2N;
      ent -= 2.0f * g * __log2f(g + 1e-8f);
    }
  }
  con *= invN;
  hom *= invN;
  ene = sqrtf(eac) * invN;
  float mu = 0.0f;
#pragma unroll
  for (int i = 0; i < 5; ++i) { P[i] *= inv2N; mu += (float)i * P[i]; }
  float s2 = 0.0f;
#pragma unroll
  for (int i = 0; i < 5; ++i) { float d = (float)i - mu; s2 = fmaf(P[i] * d, d, s2); }
  float denom = s2;   // std_i*std_j with std_i==std_j
  float cov = 0.0f;
#pragma unroll
  for (int u = 0; u < 15; ++u)
    cov += ((float)cnt[u] * invN) * ((float)LO15[u] - mu) * ((float)HI15[u] - mu);
  corr = (denom < 1e-15f) ? 1.0f : cov / fmaxf(denom, 1e-30f);
}

// Emit both packed windows' features (summed, validity-masked) to unique partial slots.
__device__ __forceinline__ void emit2(const unsigned c1[15], const unsigned c2[15], float Np,
                                      bool v1, bool v2, float* pt0, int k0, int k1) {
  float con1, hom1, ene1, cor1, ent1, con2, hom2, ene2, cor2, ent2;
  feat5(c1, Np, con1, hom1, ene1, cor1, ent1);
  feat5(c2, Np, con2, hom2, ene2, cor2, ent2);
  if (!v1) { con1 = 0; hom1 = 0; ene1 = 0; cor1 = 0; ent1 = 0; }
  if (!v2) { con2 = 0; hom2 = 0; ene2 = 0; cor2 = 0; ent2 = 0; }
  float con = wred(con1 + con2), hom = wred(hom1 + hom2), ene = wred(ene1 + ene2);
  float cor = wred(cor1 + cor2), ent = wred(ent1 + ent2);
  if ((threadIdx.x & 63) == 0) {
    const float s = 1.0f / 15376.0f;
    pt0[(8 + k0) * 128] = con * s;
    pt0[(20 + k0) * 128] = hom * s;
    pt0[(32 + k0) * 128] = ene * s;
    pt0[(44 + k0) * 128] = cor * s;
    pt0[(56 + k0) * 128] = ent * s;
    if (k1 >= 0) {
      pt0[(8 + k1) * 128] = con * s;
      pt0[(20 + k1) * 128] = hom * s;
      pt0[(32 + k1) * 128] = ene * s;
      pt0[(44 + k1) * 128] = cor * s;
      pt0[(56 + k1) * 128] = ent * s;
    }
  }
}

template<int DR>
__device__ __forceinline__ void shiftbuf(unsigned buf[][5], const unsigned c[5]) {
#pragma unroll
  for (int i = 0; i < DR - 1; ++i)
#pragma unroll
    for (int v = 0; v < 5; ++v) buf[i][v] = buf[i + 1][v];
#pragma unroll
  for (int v = 0; v < 5; ++v) buf[DR - 1][v] = c[v];
}

// One offset over the lane's 2 vertically-adjacent windows. Rows s..s+20 each LDS-loaded
// ONCE. Phase counters: A rows R<4 (w1 only), S (shared), B (w2 only).
template<int DR, int DC>
__device__ __forceinline__ void glcm_pass(const unsigned long long* mk, int s, int ly4,
                                          float Np, bool v1, bool v2, float* pt0,
                                          int k0, int k1) {
  unsigned A[15], S[15], B[15];
#pragma unroll
  for (int u = 0; u < 15; ++u) { A[u] = 0; S[u] = 0; B[u] = 0; }
  unsigned c[5];
  if (DR == 0) {
#pragma unroll 1
    for (int R = 0; R < 4; ++R)  { load_row(mk + (s + R) * 5, ly4, c); updoff<DC>(A, c, c); }
#pragma unroll 1
    for (int R = 4; R < 17; ++R) { load_row(mk + (s + R) * 5, ly4, c); updoff<DC>(S, c, c); }
#pragma unroll 1
    for (int R = 17; R < 21; ++R){ load_row(mk + (s + R) * 5, ly4, c); updoff<DC>(B, c, c); }
  } else {
    unsigned buf[DR > 0 ? DR : 1][5];
#pragma unroll
    for (int i = 0; i < DR; ++i) load_row(mk + (s + i) * 5, ly4, buf[i]);
#pragma unroll 1
    for (int R = 0; R < 4; ++R) {
      load_row(mk + (s + R + DR) * 5, ly4, c);
      updoff<DC>(A, buf[0], c);
      shiftbuf<DR>(buf, c);
    }
#pragma unroll 1
    for (int R = 4; R < 17 - DR; ++R) {
      load_row(mk + (s + R + DR) * 5, ly4, c);
      updoff<DC>(S, buf[0], c);
      shiftbuf<DR>(buf, c);
    }
#pragma unroll 1
    for (int R = 17 - DR; R < 21 - DR; ++R) {
      load_row(mk + (s + R + DR) * 5, ly4, c);
      updoff<DC>(B, buf[0], c);
      shiftbuf<DR>(buf, c);
    }
  }
#pragma unroll
  for (int u = 0; u < 15; ++u) { A[u] += S[u]; B[u] += S[u]; }
  emit2(A, B, Np, v1, v2, pt0, k0, k1);
}

// ---------- Kernel 1: whole-image mask precompute (verified R5-R7) ----------
__global__ __launch_bounds__(64)
void mask_build_kernel(const float* __restrict__ x, unsigned long long* __restrict__ mg) {
  const int lane = threadIdx.x;
  const int r = blockIdx.x;
  const int b = blockIdx.y;
  const float* xr = x + ((size_t)b * 512 + r) * 512;
  unsigned long long* mr = mg + ((size_t)b * 512 + r) * 36;

  const float T1 = 0.5f;
  const float T2 = (float)(85.384 - 53.798);
  const float T3 = 85.384f;
  const float T4 = (float)(85.384 + 53.798);

#pragma unroll 1
  for (int seg = 0; seg < 8; ++seg) {
    float xv = xr[seg * 64 + lane];
    int q = (int)(xv >= T1) + (int)(xv >= T2) + (int)(xv >= T3) + (int)(xv >= T4);
    unsigned long long b1 = __ballot(q == 1);
    unsigned long long b2 = __ballot(q == 2);
    unsigned long long b3 = __ballot(q == 3);
    unsigned long long b4 = __ballot(q == 4);
    if (lane < 4) {
      unsigned long long bv = (lane == 0) ? b1 : (lane == 1) ? b2 : (lane == 2) ? b3 : b4;
      mr[seg * 4 + lane] = bv;
    }
  }
  if (lane < 4) mr[32 + lane] = 0;  // seg 8 pad
}

// ---------- Kernel 2: features -> per-tile partials ----------
__global__ __launch_bounds__(128)
void glcm_feat_kernel(const float* __restrict__ x,
                      const unsigned long long* __restrict__ mg,
                      float* __restrict__ part) {
  __shared__ unsigned long long masks[77 * 5];  // [tile_row][lev], slot 4 pad (3080 B)

  const int tid = threadIdx.x;
  const int lane = tid & 63;
  const int wid = tid >> 6;
  const int u = blockIdx.x >> 4;
  const int ty = blockIdx.x & 15;
  const int tx = blockIdx.y;
  const int b = blockIdx.z;
  const int px0 = tx * 64;
  const int py0 = ty * 32;
  const float* xb = x + (size_t)b * 512 * 512;

  // Phase A: slice tile rows from precomputed masks (L2-hot).
  const int s0 = py0 >> 6;
  const int sh = py0 & 63;  // 0 or 32
  const unsigned long long* mgb = mg + (size_t)b * 512 * 36;
#pragma unroll 1
  for (int t = tid; t < 77 * 4; t += 128) {
    int row = t >> 2, lev = t & 3;
    int gr = px0 + row; if (gr > 511) gr = 511;
    const unsigned long long* p = mgb + (size_t)gr * 36 + s0 * 4 + lev;
    unsigned long long w0 = p[0];
    unsigned long long w1 = p[4];
    masks[row * 5 + lev] = sh ? ((w0 >> 32) | (w1 << 32)) : w0;
  }
  __syncthreads();

  // Lane = (lxp, ly): window pair wx1 = tx*16 + 2*lxp (+1); wy = ty*8 + ly.
  const int lxp = lane >> 3, ly = lane & 7;
  const int wx1 = tx * 16 + 2 * lxp;
  const int wy = ty * 8 + ly;
  const bool vy = (wy < 124);
  const bool v1 = (wx1 < 124) && vy;
  const bool v2 = (wx1 + 1 < 124) && vy;
  const int s = 8 * lxp;        // tile-local pixel row of w1
  const int ly4 = ly * 4;
  const int tile = tx * 16 + ty;                          // 0..127
  float* pt0 = part + (size_t)b * 68 * 128 + tile;        // channel ch at pt0[ch*128]

  if (u == 0) {
    if (wid == 0) {
      // ---- float stats (channels 0-3), phase-decomposed over the window pair ----
      int sp = px0 + s; if (sp > 488) sp = 488;
      int c0 = py0 + ly4; if (c0 > 492) c0 = 492;
      const float* fw = xb + (size_t)sp * 512 + c0;
      float sA = 0, qA = 0, sS = 0, qS = 0, sB = 0, qB = 0;
      float mxA = -1e30f, mnA = 1e30f, mxS = -1e30f, mnS = 1e30f, mxB = -1e30f, mnB = 1e30f;
#pragma unroll 1
      for (int r = 0; r < 21; ++r) {
        const float* p = fw + r * 512;
        const float4* p4 = (const float4*)p;
        float rs = 0, rq = 0, rmx = -1e30f, rmn = 1e30f;
#pragma unroll
        for (int w = 0; w < 4; ++w) {
          float4 f = p4[w];
          rs += f.x; rq = fmaf(f.x, f.x, rq); rmx = fmaxf(rmx, f.x); rmn = fminf(rmn, f.x);
          rs += f.y; rq = fmaf(f.y, f.y, rq); rmx = fmaxf(rmx, f.y); rmn = fminf(rmn, f.y);
          rs += f.z; rq = fmaf(f.z, f.z, rq); rmx = fmaxf(rmx, f.z); rmn = fminf(rmn, f.z);
          rs += f.w; rq = fmaf(f.w, f.w, rq); rmx = fmaxf(rmx, f.w); rmn = fminf(rmn, f.w);
        }
        float t = p[16];
        rs += t; rq = fmaf(t, t, rq); rmx = fmaxf(rmx, t); rmn = fminf(rmn, t);
        if (r < 4)       { sA += rs; qA += rq; mxA = fmaxf(mxA, rmx); mnA = fminf(mnA, rmn); }
        else if (r < 17) { sS += rs; qS += rq; mxS = fmaxf(mxS, rmx); mnS = fminf(mnS, rmn); }
        else             { sB += rs; qB += rq; mxB = fmaxf(mxB, rmx); mnB = fminf(mnB, rmn); }
      }
      float ch[4][2];
#pragma unroll
      for (int w = 0; w < 2; ++w) {
        float sum = w ? (sS + sB) : (sA + sS);
        float ssq = w ? (qS + qB) : (qA + qS);
        float mx = w ? fmaxf(mxS, mxB) : fmaxf(mxA, mxS);
        float mn = w ? fminf(mnS, mnB) : fminf(mnA, mnS);
        float mean = sum * (1.0f / 289.0f);
        float var = fmaxf(ssq * (1.0f / 289.0f) - mean * mean, 0.0f);
        float fm = mean / G_MEAN_F;
        ch[0][w] = fm;
        ch[1][w] = sqrtf(var) / G_STD_F;
        ch[2][w] = (mx - fm) / G_STD_F;
        ch[3][w] = (fm - mn) / G_STD_F;
      }
#pragma unroll
      for (int c = 0; c < 4; ++c) {
        float f = (v1 ? ch[c][0] : 0.0f) + (v2 ? ch[c][1] : 0.0f);
        f = wred(f);
        if (lane == 0) pt0[c * 128] = f * (1.0f / 15376.0f);
      }
    } else {
      // ---- value histogram (channels 4-7) from mask popcounts, phase-decomposed ----
      unsigned hA[4] = {0,0,0,0}, hS[4] = {0,0,0,0}, hB[4] = {0,0,0,0};
#pragma unroll 1
      for (int R = 0; R < 21; ++R) {
        unsigned m[5];
        load_row(masks + (s + R) * 5, ly4, m);
        unsigned* h = (R < 4) ? hA : (R < 17) ? hS : hB;
#pragma unroll
        for (int v = 0; v < 4; ++v) h[v] += __popc(m[v + 1]);
      }
      float ch[4][2];
#pragma unroll
      for (int w = 0; w < 2; ++w) {
        unsigned t1 = w ? (hS[0] + hB[0]) : (hA[0] + hS[0]);
        unsigned t2 = w ? (hS[1] + hB[1]) : (hA[1] + hS[1]);
        unsigned t3 = w ? (hS[2] + hB[2]) : (hA[2] + hS[2]);
        unsigned t4 = w ? (hS[3] + hB[3]) : (hA[3] + hS[3]);
        unsigned tot = t1 + t2 + t3 + t4;
        float ti = (tot > 0) ? 1.0f / (float)tot : 0.0f;
        ch[0][w] = (float)t1 * ti;
        ch[1][w] = (float)t2 * ti;
        ch[2][w] = (float)t3 * ti;
        ch[3][w] = (float)t4 * ti;
      }
#pragma unroll
      for (int c = 0; c < 4; ++c) {
        float f = (v1 ? ch[c][0] : 0.0f) + (v2 ? ch[c][1] : 0.0f);
        f = wred(f);
        if (lane == 0) pt0[(4 + c) * 128] = f * (1.0f / 15376.0f);
      }
    }
  } else if (u == 1) {
    if (wid == 0) glcm_pass<0, 1>(masks, s, ly4, 272.0f, v1, v2, pt0, 0, -1);
    else          glcm_pass<1, 0>(masks, s, ly4, 272.0f, v1, v2, pt0, 2, -1);
  } else if (u == 2) {
    if (wid == 0) glcm_pass<0, 2>(masks, s, ly4, 255.0f, v1, v2, pt0, 4, -1);
    else          glcm_pass<1, 1>(masks, s, ly4, 256.0f, v1, v2, pt0, 1, 5);
  } else if (u == 3) {
    if (wid == 0) glcm_pass<0, 4>(masks, s, ly4, 221.0f, v1, v2, pt0, 8, -1);
    else          glcm_pass<1, -1>(masks, s, ly4, 256.0f, v1, v2, pt0, 3, 7);
  } else if (u == 4) {
    if (wid == 0) glcm_pass<2, 0>(masks, s, ly4, 255.0f, v1, v2, pt0, 6, -1);
    else          glcm_pass<3, 3>(masks, s, ly4, 196.0f, v1, v2, pt0, 9, -1);
  } else {
    if (wid == 0) glcm_pass<4, 0>(masks, s, ly4, 221.0f, v1, v2, pt0, 10, -1);
    else          glcm_pass<3, -3>(masks, s, ly4, 196.0f, v1, v2, pt0, 11, -1);
  }
}

// ---------- Kernel 3: reduce 128 tile-partials per (batch,channel) ----------
__global__ __launch_bounds__(64)
void reduce_kernel(const float* __restrict__ part, float* __restrict__ out) {
  const int ch = blockIdx.x;
  const int b = blockIdx.y;
  const int lane = threadIdx.x;
  const float2* p = (const float2*)(part + ((size_t)b * 68 + ch) * 128);
  float2 f = p[lane];
  float v = f.x + f.y;
  v = wred(v);
  if (lane == 0) out[b * 68 + ch] = v;
}

extern "C" void kernel_launch(void* const* d_in, const int* in_sizes, int n_in,
                              void* d_out, int out_size, void* d_ws, size_t ws_size,
                              hipStream_t stream)
{
  const float* x = (const float*)d_in[0];
  float* out = (float*)d_out;
  unsigned long long* mg = (unsigned long long*)d_ws;         // 1.18 MB
  float* part = (float*)((char*)d_ws + MASK_WS_BYTES);        // 278 KB

  mask_build_kernel<<<dim3(512, 8), dim3(64), 0, stream>>>(x, mg);
  glcm_feat_kernel<<<dim3(96, 8, 8), dim3(128), 0, stream>>>(x, mg, part);
  reduce_kernel<<<dim3(68, 8), dim3(64), 0, stream>>>(part, out);
}